// Round 6
// baseline (387.262 us; speedup 1.0000x reference)
//
#include <hip/hip_runtime.h>

#define N_NODES 50000
#define N_EDGES 800000
// IN=128, HID=128, OUT=64

typedef unsigned short ushort_t;
typedef unsigned int uint_t;
typedef __attribute__((ext_vector_type(8))) short bf16x8;
typedef __attribute__((ext_vector_type(4))) float f32x4;

#define NB 196        // buckets: dst>>8, 50000/256 -> 196
#define BCAP 8192     // per-bucket capacity (avg 4082)
#define NBLK_BUCKET ((N_EDGES + 8191) / 8192)

// ---------------- workspace layout ----------------
// int region (int offsets):
//   cnt     [50000]   @ 0
//   rowptr  [50001]   @ 100000
//   eidx    [800000]  @ 150016
//   partial [64]      @ 950016
//   bcnt    [196]     @ 950080
// bf16 region (ushort offsets into ws):
//   wT    [49152]     @ 1900672   (WsT1 16384 | WnT1 16384 | WnT2 8192 | WsT2 8192)
//   featb [50000*128] @ 2000000
//   agg1b [50000*128] @ 8400000
//   h1b   [50000*128] @ 14800000   (bucket u32[196*8192] aliased here pre-gemm1)
//   p2b   [50000*64]  @ 21200000
#define IOFF_CNT     0
#define IOFF_ROWPTR  100000
#define IOFF_EIDX    150016
#define IOFF_PART    950016
#define IOFF_BCNT    950080
#define UOFF_WT      1900672
#define UOFF_FEATB   2000000
#define UOFF_AGG1B   8400000
#define UOFF_H1B     14800000
#define UOFF_P2B     21200000

__device__ __forceinline__ float bf2f(uint_t u) {
    return __uint_as_float(u << 16);
}
__device__ __forceinline__ uint_t f2bf(float f) {
    uint_t x = __float_as_uint(f);
    return (x + 0x7FFFu + ((x >> 16) & 1u)) >> 16;  // RNE
}

__global__ __launch_bounds__(256) void hist_kernel(const int* __restrict__ dst,
                                                   int* __restrict__ cnt) {
    int e = blockIdx.x * 256 + threadIdx.x;
    if (e < N_EDGES) atomicAdd(&cnt[dst[e]], 1);
}

__global__ __launch_bounds__(1024) void scan_part(const int* __restrict__ cnt,
                                                  int* __restrict__ rowptr,
                                                  int* __restrict__ partial) {
    __shared__ int sh[1024];
    int b = blockIdx.x, tid = threadIdx.x;
    int i = b * 1024 + tid;
    int v = (i < N_NODES) ? cnt[i] : 0;
    sh[tid] = v;
    __syncthreads();
    for (int off = 1; off < 1024; off <<= 1) {
        int t = (tid >= off) ? sh[tid - off] : 0;
        __syncthreads();
        sh[tid] += t;
        __syncthreads();
    }
    if (i < N_NODES) rowptr[i] = sh[tid] - v;  // local exclusive
    if (tid == 1023) partial[b] = sh[1023];
}

__global__ __launch_bounds__(64) void scan_top(int* __restrict__ partial,
                                               int* __restrict__ rowptr) {
    int l = threadIdx.x;
    int nblk = (N_NODES + 1023) / 1024;
    int v = (l < nblk) ? partial[l] : 0;
    int incl = v;
    for (int off = 1; off < 64; off <<= 1) {
        int t = __shfl_up(incl, off);
        if (l >= off) incl += t;
    }
    partial[l] = incl - v;  // exclusive base
    if (l == 63) rowptr[N_NODES] = incl;
}

__global__ __launch_bounds__(1024) void scan_add(int* __restrict__ rowptr,
                                                 const int* __restrict__ partial) {
    int i = blockIdx.x * 1024 + threadIdx.x;
    if (i < N_NODES) rowptr[i] += partial[blockIdx.x];
}

// ---- two-phase bucketed CSR fill (replaces scattered fill_kernel) ----
// phase 1: LDS-staged bucket append, wave-cooperative coalesced flush
__global__ __launch_bounds__(256) void bucket_kernel(const int* __restrict__ src,
                                                     const int* __restrict__ dst,
                                                     uint_t* __restrict__ bucket,
                                                     int* __restrict__ bcnt) {
    __shared__ uint_t stage[NB][128];
    __shared__ int lcnt[NB];
    int tid = threadIdx.x;
    for (int i = tid; i < NB; i += 256) lcnt[i] = 0;
    __syncthreads();
    int e0 = blockIdx.x * 8192;
    for (int i = tid; i < 8192; i += 256) {
        int e = e0 + i;
        if (e < N_EDGES) {
            int d = dst[e], s = src[e];
            uint_t v = ((uint_t)d << 16) | (uint_t)s;
            int b = d >> 8;
            int slot = atomicAdd(&lcnt[b], 1);
            if (slot < 128) {
                stage[b][slot] = v;
            } else {  // overflow fallback (statistically ~never)
                int p = atomicAdd(&bcnt[b], 1);
                bucket[(long)b * BCAP + p] = v;
            }
        }
    }
    __syncthreads();
    int wid = tid >> 6, lane = tid & 63;
    for (int b = wid; b < NB; b += 4) {
        int n = min(lcnt[b], 128);
        int base = 0;
        if (lane == 0 && n > 0) base = atomicAdd(&bcnt[b], n);
        base = __shfl(base, 0);
        for (int i = lane; i < n; i += 64)
            bucket[(long)b * BCAP + base + i] = stage[b][i];
    }
}

// phase 2: one block per bucket; eidx writes confined to one contiguous range
__global__ __launch_bounds__(256) void fill_bucket_kernel(const uint_t* __restrict__ bucket,
                                                          const int* __restrict__ bcnt,
                                                          const int* __restrict__ rowptr,
                                                          int* __restrict__ eidx) {
    __shared__ int fp[256];
    int b = blockIdx.x;
    int tid = threadIdx.x;
    fp[tid] = 0;
    __syncthreads();
    int n = bcnt[b];
    int nodebase = b << 8;
    for (int i = tid; i < n; i += 256) {
        uint_t v = bucket[(long)b * BCAP + i];
        int d = v >> 16, s = v & 0xFFFF;
        int off = atomicAdd(&fp[d - nodebase], 1);
        eidx[rowptr[d] + off] = s;
    }
}

// f32 -> bf16, 4 floats/thread
__global__ __launch_bounds__(256) void cvt_kernel(const float* __restrict__ x,
                                                  ushort_t* __restrict__ y, int n4) {
    int i = blockIdx.x * 256 + threadIdx.x;
    if (i >= n4) return;
    float4 v = ((const float4*)x)[i];
    uint2 o;
    o.x = f2bf(v.x) | (f2bf(v.y) << 16);
    o.y = f2bf(v.z) | (f2bf(v.w) << 16);
    ((uint2*)y)[i] = o;
}

// transpose+convert all 4 weight mats into wT (bf16)
__global__ __launch_bounds__(256) void wprep_kernel(const float* __restrict__ Ws1,
                                                    const float* __restrict__ Wn1,
                                                    const float* __restrict__ Ws2,
                                                    const float* __restrict__ Wn2,
                                                    ushort_t* __restrict__ wT) {
    int i = blockIdx.x * 256 + threadIdx.x;
    if (i >= 49152) return;
    float v;
    if (i < 16384) {
        int n = i >> 7, k = i & 127;
        v = Ws1[k * 128 + n];
    } else if (i < 32768) {
        int j = i - 16384, n = j >> 7, k = j & 127;
        v = Wn1[k * 128 + n];
    } else if (i < 40960) {
        int j = i - 32768, n = j >> 7, k = j & 127;
        v = Wn2[k * 64 + n];
    } else {
        int j = i - 40960, n = j >> 7, k = j & 127;
        v = Ws2[k * 64 + n];
    }
    wT[i] = (ushort_t)f2bf(v);
}

// one wave per node; lane handles 2 cols (bf16x2 = 4B); agg1b = mean of neighbor rows
__global__ __launch_bounds__(256) void gather128_kernel(const int* __restrict__ rowptr,
                                                        const int* __restrict__ eidx,
                                                        const ushort_t* __restrict__ xb,
                                                        ushort_t* __restrict__ aggb) {
    int node = blockIdx.x * 4 + (threadIdx.x >> 6);
    int lane = threadIdx.x & 63;
    if (node >= N_NODES) return;
    int beg = rowptr[node], end = rowptr[node + 1];
    float ax0 = 0.f, ay0 = 0.f, ax1 = 0.f, ay1 = 0.f;
    int e = beg;
    for (; e + 1 < end; e += 2) {
        int s0 = eidx[e], s1 = eidx[e + 1];
        uint_t v0 = *(const uint_t*)(xb + (long)s0 * 128 + lane * 2);
        uint_t v1 = *(const uint_t*)(xb + (long)s1 * 128 + lane * 2);
        ax0 += bf2f(v0 & 0xffffu); ay0 += bf2f(v0 >> 16);
        ax1 += bf2f(v1 & 0xffffu); ay1 += bf2f(v1 >> 16);
    }
    if (e < end) {
        uint_t v0 = *(const uint_t*)(xb + (long)eidx[e] * 128 + lane * 2);
        ax0 += bf2f(v0 & 0xffffu); ay0 += bf2f(v0 >> 16);
    }
    float inv = (end > beg) ? 1.0f / (float)(end - beg) : 0.f;
    uint_t o = f2bf((ax0 + ax1) * inv) | (f2bf((ay0 + ay1) * inv) << 16);
    *(uint_t*)(aggb + (long)node * 128 + lane * 2) = o;
}

// one wave per node; lane = 1 col of 64; out[node] += mean(p2b[neigh]) (f32 out)
__global__ __launch_bounds__(256) void gather64_add_kernel(const int* __restrict__ rowptr,
                                                           const int* __restrict__ eidx,
                                                           const ushort_t* __restrict__ p2b,
                                                           float* __restrict__ out) {
    int node = blockIdx.x * 4 + (threadIdx.x >> 6);
    int lane = threadIdx.x & 63;
    if (node >= N_NODES) return;
    int beg = rowptr[node], end = rowptr[node + 1];
    float a0 = 0.f, a1 = 0.f;
    int e = beg;
    for (; e + 1 < end; e += 2) {
        a0 += bf2f((uint_t)p2b[(long)eidx[e] * 64 + lane]);
        a1 += bf2f((uint_t)p2b[(long)eidx[e + 1] * 64 + lane]);
    }
    if (e < end) a0 += bf2f((uint_t)p2b[(long)eidx[e] * 64 + lane]);
    float inv = (end > beg) ? 1.0f / (float)(end - beg) : 0.f;
    out[(long)node * 64 + lane] += (a0 + a1) * inv;
}

// ---------------- MFMA GEMMs (no LDS; frags straight from global) ----------------
// A frag (16x16x32 bf16): row = lane&15, k = (lane>>4)*8 + e  -> 16B contiguous
// B frag: col = lane&15, same k                               -> 16B contiguous in W^T
// D frag: col = lane&15, row = (lane>>4)*4 + reg

__global__ __launch_bounds__(256) void gemm1_mfma(const ushort_t* __restrict__ featb,
                                                  const ushort_t* __restrict__ agg1b,
                                                  const ushort_t* __restrict__ wT,
                                                  const float* __restrict__ b,
                                                  ushort_t* __restrict__ h1b) {
    int lane = threadIdx.x & 63;
    int w = threadIdx.x >> 6;
    int mbase = blockIdx.x * 128 + w * 32;
    int lr = lane & 15;
    int kg = (lane >> 4) * 8;

    long r0 = mbase + lr;
    long r1 = mbase + 16 + lr;
    if (r0 > N_NODES - 1) r0 = N_NODES - 1;
    if (r1 > N_NODES - 1) r1 = N_NODES - 1;

    f32x4 acc[2][8];
#pragma unroll
    for (int mt = 0; mt < 2; ++mt)
#pragma unroll
        for (int nt = 0; nt < 8; ++nt) acc[mt][nt] = (f32x4){0.f, 0.f, 0.f, 0.f};

#pragma unroll
    for (int pass = 0; pass < 2; ++pass) {
        const ushort_t* a = pass ? agg1b : featb;
        const ushort_t* wt = wT + pass * (128 * 128);
#pragma unroll
        for (int ks = 0; ks < 4; ++ks) {
            int k = ks * 32 + kg;
            bf16x8 a0 = *(const bf16x8*)(a + r0 * 128 + k);
            bf16x8 a1 = *(const bf16x8*)(a + r1 * 128 + k);
#pragma unroll
            for (int nt = 0; nt < 8; ++nt) {
                bf16x8 bb = *(const bf16x8*)(wt + (nt * 16 + lr) * 128 + k);
                acc[0][nt] = __builtin_amdgcn_mfma_f32_16x16x32_bf16(a0, bb, acc[0][nt], 0, 0, 0);
                acc[1][nt] = __builtin_amdgcn_mfma_f32_16x16x32_bf16(a1, bb, acc[1][nt], 0, 0, 0);
            }
        }
    }

    int drow = (lane >> 4) * 4;
#pragma unroll
    for (int nt = 0; nt < 8; ++nt) {
        int n = nt * 16 + lr;
        float bias = b[n];
#pragma unroll
        for (int mt = 0; mt < 2; ++mt) {
#pragma unroll
            for (int r = 0; r < 4; ++r) {
                int row = mbase + mt * 16 + drow + r;
                if (row < N_NODES) {
                    float v = fmaxf(acc[mt][nt][r] + bias, 0.f);
                    h1b[(long)row * 128 + n] = (ushort_t)f2bf(v);
                }
            }
        }
    }
}

// fused layer-2: p2b = bf16(h1b@Wn2); out = h1b@Ws2 + b2  (A-frags shared)
__global__ __launch_bounds__(256) void gemm2_mfma(const ushort_t* __restrict__ h1b,
                                                  const ushort_t* __restrict__ wT2,  // [WnT2 | WsT2]
                                                  const float* __restrict__ b2,
                                                  ushort_t* __restrict__ p2b,
                                                  float* __restrict__ out) {
    int lane = threadIdx.x & 63;
    int w = threadIdx.x >> 6;
    int mbase = blockIdx.x * 128 + w * 32;
    int lr = lane & 15;
    int kg = (lane >> 4) * 8;

    long r0 = mbase + lr;
    long r1 = mbase + 16 + lr;
    if (r0 > N_NODES - 1) r0 = N_NODES - 1;
    if (r1 > N_NODES - 1) r1 = N_NODES - 1;

    f32x4 accP[2][4], accO[2][4];
#pragma unroll
    for (int mt = 0; mt < 2; ++mt)
#pragma unroll
        for (int nt = 0; nt < 4; ++nt) {
            accP[mt][nt] = (f32x4){0.f, 0.f, 0.f, 0.f};
            accO[mt][nt] = (f32x4){0.f, 0.f, 0.f, 0.f};
        }

#pragma unroll
    for (int ks = 0; ks < 4; ++ks) {
        int k = ks * 32 + kg;
        bf16x8 a0 = *(const bf16x8*)(h1b + r0 * 128 + k);
        bf16x8 a1 = *(const bf16x8*)(h1b + r1 * 128 + k);
#pragma unroll
        for (int nt = 0; nt < 4; ++nt) {
            bf16x8 bn = *(const bf16x8*)(wT2 + (nt * 16 + lr) * 128 + k);
            bf16x8 bs = *(const bf16x8*)(wT2 + 8192 + (nt * 16 + lr) * 128 + k);
            accP[0][nt] = __builtin_amdgcn_mfma_f32_16x16x32_bf16(a0, bn, accP[0][nt], 0, 0, 0);
            accP[1][nt] = __builtin_amdgcn_mfma_f32_16x16x32_bf16(a1, bn, accP[1][nt], 0, 0, 0);
            accO[0][nt] = __builtin_amdgcn_mfma_f32_16x16x32_bf16(a0, bs, accO[0][nt], 0, 0, 0);
            accO[1][nt] = __builtin_amdgcn_mfma_f32_16x16x32_bf16(a1, bs, accO[1][nt], 0, 0, 0);
        }
    }

    int drow = (lane >> 4) * 4;
#pragma unroll
    for (int nt = 0; nt < 4; ++nt) {
        int n = nt * 16 + lr;
        float bias = b2[n];
#pragma unroll
        for (int mt = 0; mt < 2; ++mt) {
#pragma unroll
            for (int r = 0; r < 4; ++r) {
                int row = mbase + mt * 16 + drow + r;
                if (row < N_NODES) {
                    p2b[(long)row * 64 + n] = (ushort_t)f2bf(accP[mt][nt][r]);
                    out[(long)row * 64 + n] = accO[mt][nt][r] + bias;
                }
            }
        }
    }
}

extern "C" void kernel_launch(void* const* d_in, const int* in_sizes, int n_in,
                              void* d_out, int out_size, void* d_ws, size_t ws_size,
                              hipStream_t stream) {
    const float* feat = (const float*)d_in[0];
    const int* src    = (const int*)d_in[1];
    const int* dst    = (const int*)d_in[2];
    const float* Ws1  = (const float*)d_in[3];
    const float* Wn1  = (const float*)d_in[4];
    const float* b1   = (const float*)d_in[5];
    const float* Ws2  = (const float*)d_in[6];
    const float* Wn2  = (const float*)d_in[7];
    const float* b2   = (const float*)d_in[8];
    float* out = (float*)d_out;

    int* wsi      = (int*)d_ws;
    ushort_t* wsu = (ushort_t*)d_ws;
    int* cnt      = wsi + IOFF_CNT;
    int* rowptr   = wsi + IOFF_ROWPTR;
    int* eidx     = wsi + IOFF_EIDX;
    int* partial  = wsi + IOFF_PART;
    int* bcnt     = wsi + IOFF_BCNT;
    ushort_t* wT    = wsu + UOFF_WT;
    ushort_t* featb = wsu + UOFF_FEATB;
    ushort_t* agg1b = wsu + UOFF_AGG1B;
    ushort_t* h1b   = wsu + UOFF_H1B;
    ushort_t* p2b   = wsu + UOFF_P2B;
    uint_t* bucket  = (uint_t*)(wsu + UOFF_H1B);  // aliased: dead before gemm1 writes h1b

    // zero cnt (50000 ints) and bcnt (196 ints)
    hipMemsetAsync(cnt, 0, 50000 * sizeof(int), stream);
    hipMemsetAsync(bcnt, 0, NB * sizeof(int), stream);

    // weight transpose+convert; feat -> bf16 (independent of CSR build)
    wprep_kernel<<<(49152 + 255) / 256, 256, 0, stream>>>(Ws1, Wn1, Ws2, Wn2, wT);
    cvt_kernel<<<(N_NODES * 128 / 4 + 255) / 256, 256, 0, stream>>>(feat, featb, N_NODES * 128 / 4);

    // ---- build CSR (dst-sorted) via bucketed two-phase fill ----
    hist_kernel<<<(N_EDGES + 255) / 256, 256, 0, stream>>>(dst, cnt);
    {
        int nblk = (N_NODES + 1023) / 1024;
        scan_part<<<nblk, 1024, 0, stream>>>(cnt, rowptr, partial);
        scan_top<<<1, 64, 0, stream>>>(partial, rowptr);
        scan_add<<<nblk, 1024, 0, stream>>>(rowptr, partial);
    }
    bucket_kernel<<<NBLK_BUCKET, 256, 0, stream>>>(src, dst, bucket, bcnt);
    fill_bucket_kernel<<<NB, 256, 0, stream>>>(bucket, bcnt, rowptr, eidx);

    // ---- layer 1 ----
    gather128_kernel<<<(N_NODES + 3) / 4, 256, 0, stream>>>(rowptr, eidx, featb, agg1b);
    gemm1_mfma<<<(N_NODES + 127) / 128, 256, 0, stream>>>(featb, agg1b, wT, b1, h1b);

    // ---- layer 2 (fused dual GEMM, aggregate-after-matmul) ----
    gemm2_mfma<<<(N_NODES + 127) / 128, 256, 0, stream>>>(h1b, wT + 32768, b2, p2b, out);
    gather64_add_kernel<<<(N_NODES + 3) / 4, 256, 0, stream>>>(rowptr, eidx, p2b, out);
}

// Round 8
// 267.014 us; speedup vs baseline: 1.4503x; 1.4503x over previous
//
#include <hip/hip_runtime.h>

#define N_NODES 50000
#define N_EDGES 800000
// IN=128, HID=128, OUT=64

typedef unsigned short ushort_t;
typedef unsigned int uint_t;
typedef __attribute__((ext_vector_type(8))) short bf16x8;
typedef __attribute__((ext_vector_type(4))) float f32x4;

#define NB 196        // buckets: dst>>8 (256 nodes per bucket)
#define BCAP 6144     // per-bucket capacity (avg 4082, +safety)
#define SDEPTH 16     // LDS staging depth per bucket
#define EPB 1024      // edges per bucket_kernel block
#define NBLK_BUCKET ((N_EDGES + EPB - 1) / EPB)

// ---------------- workspace layout ----------------
// int region (int offsets; bytes = x4):
//   rowptr  [50001]   @ 100000   (bytes 400000..600004)
//   eidx    [800000]  @ 150016   (bytes 600064..3800064)
//   bbase   [256]     @ 950016   (bytes 3800064..3801088)
//   bcnt    [196]     @ 950528   (bytes 3802112..3802896)
// bf16 region (ushort offsets; bytes = x2):
//   wT    [49152]     @ 1920000  (bytes 3840000..3938304)  <- moved past bcnt (R7 overlap bug)
//   featb [50000*128] @ 2000000  (bytes 4000000..16800000)
//   agg1b [50000*128] @ 8400000  (bytes 16800000..29600000)
//   h1b   [50000*128] @ 14800000 (bytes 29600000..42400000; bucket u32[196*6144]=4.8MB aliased pre-gemm1)
//   p2b   [50000*64]  @ 21200000 (bytes 42400000..48800000)
#define IOFF_ROWPTR  100000
#define IOFF_EIDX    150016
#define IOFF_BBASE   950016
#define IOFF_BCNT    950528
#define UOFF_WT      1920000
#define UOFF_FEATB   2000000
#define UOFF_AGG1B   8400000
#define UOFF_H1B     14800000
#define UOFF_P2B     21200000

__device__ __forceinline__ float bf2f(uint_t u) {
    return __uint_as_float(u << 16);
}
__device__ __forceinline__ uint_t f2bf(float f) {
    uint_t x = __float_as_uint(f);
    return (x + 0x7FFFu + ((x >> 16) & 1u)) >> 16;  // RNE
}

// ---- bucketed CSR build, occupancy-friendly ----
// phase 1: partition edges into 196 buckets (LDS-staged, coalesced flush).
// 782 blocks x 1024 edges; LDS ~14KB -> ~3 blocks/CU (12 waves/CU).
__global__ __launch_bounds__(256) void bucket_kernel(const int* __restrict__ src,
                                                     const int* __restrict__ dst,
                                                     uint_t* __restrict__ bucket,
                                                     int* __restrict__ bcnt) {
    __shared__ uint_t stage[NB][SDEPTH];
    __shared__ int lcnt[NB];
    __shared__ int gbase[NB];
    int tid = threadIdx.x;
    for (int i = tid; i < NB; i += 256) lcnt[i] = 0;
    __syncthreads();
    int e0 = blockIdx.x * EPB;
#pragma unroll
    for (int it = 0; it < EPB / 256; ++it) {
        int e = e0 + it * 256 + tid;
        if (e < N_EDGES) {
            int d = dst[e], s = src[e];
            uint_t v = ((uint_t)d << 16) | (uint_t)s;
            int b = d >> 8;
            int slot = atomicAdd(&lcnt[b], 1);
            if (slot < SDEPTH) {
                stage[b][slot] = v;
            } else {  // rare overflow: direct reservation
                int p = atomicAdd(&bcnt[b], 1);
                bucket[(long)b * BCAP + p] = v;
            }
        }
    }
    __syncthreads();
    // parallel flush reservation: 196 atomics issued concurrently
    if (tid < NB) {
        int n = min(lcnt[tid], SDEPTH);
        gbase[tid] = (n > 0) ? atomicAdd(&bcnt[tid], n) : 0;
    }
    __syncthreads();
    // cooperative copy-out: (bucket, slot) pairs flattened across the block
    for (int s = tid; s < NB * SDEPTH; s += 256) {
        int b = s >> 4, i = s & (SDEPTH - 1);
        if (i < min(lcnt[b], SDEPTH))
            bucket[(long)b * BCAP + gbase[b] + i] = stage[b][i];
    }
}

// phase 2: tiny scan of 196 bucket counts -> bucket bases; grand total
__global__ __launch_bounds__(256) void scan196(const int* __restrict__ bcnt,
                                               int* __restrict__ bbase,
                                               int* __restrict__ rowptr) {
    __shared__ int sh[256];
    int tid = threadIdx.x;
    int v = (tid < NB) ? bcnt[tid] : 0;
    sh[tid] = v;
    __syncthreads();
    for (int off = 1; off < 256; off <<= 1) {
        int t = (tid >= off) ? sh[tid - off] : 0;
        __syncthreads();
        sh[tid] += t;
        __syncthreads();
    }
    if (tid < NB) bbase[tid] = sh[tid] - v;  // exclusive base
    if (tid == NB - 1) rowptr[N_NODES] = sh[tid];
}

// phase 3: per-bucket local CSR: dst-hist + scan in LDS -> rowptr + eidx.
// eidx writes confined to one contiguous ~16KB range per block.
__global__ __launch_bounds__(512) void fill_bucket(const uint_t* __restrict__ bucket,
                                                   const int* __restrict__ bcnt,
                                                   const int* __restrict__ bbase,
                                                   int* __restrict__ rowptr,
                                                   int* __restrict__ eidx) {
    __shared__ int hist[256];
    __shared__ int excl[256];
    __shared__ int fp[256];
    int b = blockIdx.x, tid = threadIdx.x;
    if (tid < 256) { hist[tid] = 0; fp[tid] = 0; }
    __syncthreads();
    int n = bcnt[b];
    int base = bbase[b];
    int nodebase = b << 8;
    const uint_t* bk = bucket + (long)b * BCAP;
    for (int i = tid; i < n; i += 512) {
        int d = (int)(bk[i] >> 16) - nodebase;
        atomicAdd(&hist[d], 1);
    }
    __syncthreads();
    int v = 0;
    if (tid < 256) { v = hist[tid]; excl[tid] = v; }
    __syncthreads();
    for (int off = 1; off < 256; off <<= 1) {
        int t = 0;
        if (tid < 256 && tid >= off) t = excl[tid - off];
        __syncthreads();
        if (tid < 256) excl[tid] += t;
        __syncthreads();
    }
    if (tid < 256) {
        excl[tid] -= v;  // inclusive -> exclusive
        int node = nodebase + tid;
        if (node < N_NODES) rowptr[node] = base + excl[tid];
    }
    __syncthreads();
    for (int i = tid; i < n; i += 512) {
        uint_t vv = bk[i];
        int d = (int)(vv >> 16) - nodebase;
        int off = atomicAdd(&fp[d], 1);
        eidx[base + excl[d] + off] = (int)(vv & 0xFFFFu);
    }
}

// f32 -> bf16, 4 floats/thread
__global__ __launch_bounds__(256) void cvt_kernel(const float* __restrict__ x,
                                                  ushort_t* __restrict__ y, int n4) {
    int i = blockIdx.x * 256 + threadIdx.x;
    if (i >= n4) return;
    float4 v = ((const float4*)x)[i];
    uint2 o;
    o.x = f2bf(v.x) | (f2bf(v.y) << 16);
    o.y = f2bf(v.z) | (f2bf(v.w) << 16);
    ((uint2*)y)[i] = o;
}

// transpose+convert all 4 weight mats into wT (bf16)
__global__ __launch_bounds__(256) void wprep_kernel(const float* __restrict__ Ws1,
                                                    const float* __restrict__ Wn1,
                                                    const float* __restrict__ Ws2,
                                                    const float* __restrict__ Wn2,
                                                    ushort_t* __restrict__ wT) {
    int i = blockIdx.x * 256 + threadIdx.x;
    if (i >= 49152) return;
    float v;
    if (i < 16384) {
        int n = i >> 7, k = i & 127;
        v = Ws1[k * 128 + n];
    } else if (i < 32768) {
        int j = i - 16384, n = j >> 7, k = j & 127;
        v = Wn1[k * 128 + n];
    } else if (i < 40960) {
        int j = i - 32768, n = j >> 7, k = j & 127;
        v = Wn2[k * 64 + n];
    } else {
        int j = i - 40960, n = j >> 7, k = j & 127;
        v = Ws2[k * 64 + n];
    }
    wT[i] = (ushort_t)f2bf(v);
}

// one wave per node; lane handles 2 cols (bf16x2 = 4B); agg1b = mean of neighbor rows
__global__ __launch_bounds__(256) void gather128_kernel(const int* __restrict__ rowptr,
                                                        const int* __restrict__ eidx,
                                                        const ushort_t* __restrict__ xb,
                                                        ushort_t* __restrict__ aggb) {
    int node = blockIdx.x * 4 + (threadIdx.x >> 6);
    int lane = threadIdx.x & 63;
    if (node >= N_NODES) return;
    int beg = rowptr[node], end = rowptr[node + 1];
    float ax0 = 0.f, ay0 = 0.f, ax1 = 0.f, ay1 = 0.f;
    int e = beg;
    for (; e + 1 < end; e += 2) {
        int s0 = eidx[e], s1 = eidx[e + 1];
        uint_t v0 = *(const uint_t*)(xb + (long)s0 * 128 + lane * 2);
        uint_t v1 = *(const uint_t*)(xb + (long)s1 * 128 + lane * 2);
        ax0 += bf2f(v0 & 0xffffu); ay0 += bf2f(v0 >> 16);
        ax1 += bf2f(v1 & 0xffffu); ay1 += bf2f(v1 >> 16);
    }
    if (e < end) {
        uint_t v0 = *(const uint_t*)(xb + (long)eidx[e] * 128 + lane * 2);
        ax0 += bf2f(v0 & 0xffffu); ay0 += bf2f(v0 >> 16);
    }
    float inv = (end > beg) ? 1.0f / (float)(end - beg) : 0.f;
    uint_t o = f2bf((ax0 + ax1) * inv) | (f2bf((ay0 + ay1) * inv) << 16);
    *(uint_t*)(aggb + (long)node * 128 + lane * 2) = o;
}

// one wave per node; lane = 1 col of 64; out[node] += mean(p2b[neigh]) (f32 out)
__global__ __launch_bounds__(256) void gather64_add_kernel(const int* __restrict__ rowptr,
                                                           const int* __restrict__ eidx,
                                                           const ushort_t* __restrict__ p2b,
                                                           float* __restrict__ out) {
    int node = blockIdx.x * 4 + (threadIdx.x >> 6);
    int lane = threadIdx.x & 63;
    if (node >= N_NODES) return;
    int beg = rowptr[node], end = rowptr[node + 1];
    float a0 = 0.f, a1 = 0.f;
    int e = beg;
    for (; e + 1 < end; e += 2) {
        a0 += bf2f((uint_t)p2b[(long)eidx[e] * 64 + lane]);
        a1 += bf2f((uint_t)p2b[(long)eidx[e + 1] * 64 + lane]);
    }
    if (e < end) a0 += bf2f((uint_t)p2b[(long)eidx[e] * 64 + lane]);
    float inv = (end > beg) ? 1.0f / (float)(end - beg) : 0.f;
    out[(long)node * 64 + lane] += (a0 + a1) * inv;
}

// ---------------- MFMA GEMMs (no LDS; frags straight from global) ----------------
// A frag (16x16x32 bf16): row = lane&15, k = (lane>>4)*8 + e  -> 16B contiguous
// B frag: col = lane&15, same k                               -> 16B contiguous in W^T
// D frag: col = lane&15, row = (lane>>4)*4 + reg

__global__ __launch_bounds__(256) void gemm1_mfma(const ushort_t* __restrict__ featb,
                                                  const ushort_t* __restrict__ agg1b,
                                                  const ushort_t* __restrict__ wT,
                                                  const float* __restrict__ b,
                                                  ushort_t* __restrict__ h1b) {
    int lane = threadIdx.x & 63;
    int w = threadIdx.x >> 6;
    int mbase = blockIdx.x * 128 + w * 32;
    int lr = lane & 15;
    int kg = (lane >> 4) * 8;

    long r0 = mbase + lr;
    long r1 = mbase + 16 + lr;
    if (r0 > N_NODES - 1) r0 = N_NODES - 1;
    if (r1 > N_NODES - 1) r1 = N_NODES - 1;

    f32x4 acc[2][8];
#pragma unroll
    for (int mt = 0; mt < 2; ++mt)
#pragma unroll
        for (int nt = 0; nt < 8; ++nt) acc[mt][nt] = (f32x4){0.f, 0.f, 0.f, 0.f};

#pragma unroll
    for (int pass = 0; pass < 2; ++pass) {
        const ushort_t* a = pass ? agg1b : featb;
        const ushort_t* wt = wT + pass * (128 * 128);
#pragma unroll
        for (int ks = 0; ks < 4; ++ks) {
            int k = ks * 32 + kg;
            bf16x8 a0 = *(const bf16x8*)(a + r0 * 128 + k);
            bf16x8 a1 = *(const bf16x8*)(a + r1 * 128 + k);
#pragma unroll
            for (int nt = 0; nt < 8; ++nt) {
                bf16x8 bb = *(const bf16x8*)(wt + (nt * 16 + lr) * 128 + k);
                acc[0][nt] = __builtin_amdgcn_mfma_f32_16x16x32_bf16(a0, bb, acc[0][nt], 0, 0, 0);
                acc[1][nt] = __builtin_amdgcn_mfma_f32_16x16x32_bf16(a1, bb, acc[1][nt], 0, 0, 0);
            }
        }
    }

    int drow = (lane >> 4) * 4;
#pragma unroll
    for (int nt = 0; nt < 8; ++nt) {
        int n = nt * 16 + lr;
        float bias = b[n];
#pragma unroll
        for (int mt = 0; mt < 2; ++mt) {
#pragma unroll
            for (int r = 0; r < 4; ++r) {
                int row = mbase + mt * 16 + drow + r;
                if (row < N_NODES) {
                    float v = fmaxf(acc[mt][nt][r] + bias, 0.f);
                    h1b[(long)row * 128 + n] = (ushort_t)f2bf(v);
                }
            }
        }
    }
}

// fused layer-2: p2b = bf16(h1b@Wn2); out = h1b@Ws2 + b2  (A-frags shared)
__global__ __launch_bounds__(256) void gemm2_mfma(const ushort_t* __restrict__ h1b,
                                                  const ushort_t* __restrict__ wT2,  // [WnT2 | WsT2]
                                                  const float* __restrict__ b2,
                                                  ushort_t* __restrict__ p2b,
                                                  float* __restrict__ out) {
    int lane = threadIdx.x & 63;
    int w = threadIdx.x >> 6;
    int mbase = blockIdx.x * 128 + w * 32;
    int lr = lane & 15;
    int kg = (lane >> 4) * 8;

    long r0 = mbase + lr;
    long r1 = mbase + 16 + lr;
    if (r0 > N_NODES - 1) r0 = N_NODES - 1;
    if (r1 > N_NODES - 1) r1 = N_NODES - 1;

    f32x4 accP[2][4], accO[2][4];
#pragma unroll
    for (int mt = 0; mt < 2; ++mt)
#pragma unroll
        for (int nt = 0; nt < 4; ++nt) {
            accP[mt][nt] = (f32x4){0.f, 0.f, 0.f, 0.f};
            accO[mt][nt] = (f32x4){0.f, 0.f, 0.f, 0.f};
        }

#pragma unroll
    for (int ks = 0; ks < 4; ++ks) {
        int k = ks * 32 + kg;
        bf16x8 a0 = *(const bf16x8*)(h1b + r0 * 128 + k);
        bf16x8 a1 = *(const bf16x8*)(h1b + r1 * 128 + k);
#pragma unroll
        for (int nt = 0; nt < 4; ++nt) {
            bf16x8 bn = *(const bf16x8*)(wT2 + (nt * 16 + lr) * 128 + k);
            bf16x8 bs = *(const bf16x8*)(wT2 + 8192 + (nt * 16 + lr) * 128 + k);
            accP[0][nt] = __builtin_amdgcn_mfma_f32_16x16x32_bf16(a0, bn, accP[0][nt], 0, 0, 0);
            accP[1][nt] = __builtin_amdgcn_mfma_f32_16x16x32_bf16(a1, bn, accP[1][nt], 0, 0, 0);
            accO[0][nt] = __builtin_amdgcn_mfma_f32_16x16x32_bf16(a0, bs, accO[0][nt], 0, 0, 0);
            accO[1][nt] = __builtin_amdgcn_mfma_f32_16x16x32_bf16(a1, bs, accO[1][nt], 0, 0, 0);
        }
    }

    int drow = (lane >> 4) * 4;
#pragma unroll
    for (int nt = 0; nt < 4; ++nt) {
        int n = nt * 16 + lr;
        float bias = b2[n];
#pragma unroll
        for (int mt = 0; mt < 2; ++mt) {
#pragma unroll
            for (int r = 0; r < 4; ++r) {
                int row = mbase + mt * 16 + drow + r;
                if (row < N_NODES) {
                    p2b[(long)row * 64 + n] = (ushort_t)f2bf(accP[mt][nt][r]);
                    out[(long)row * 64 + n] = accO[mt][nt][r] + bias;
                }
            }
        }
    }
}

extern "C" void kernel_launch(void* const* d_in, const int* in_sizes, int n_in,
                              void* d_out, int out_size, void* d_ws, size_t ws_size,
                              hipStream_t stream) {
    const float* feat = (const float*)d_in[0];
    const int* src    = (const int*)d_in[1];
    const int* dst    = (const int*)d_in[2];
    const float* Ws1  = (const float*)d_in[3];
    const float* Wn1  = (const float*)d_in[4];
    const float* b1   = (const float*)d_in[5];
    const float* Ws2  = (const float*)d_in[6];
    const float* Wn2  = (const float*)d_in[7];
    const float* b2   = (const float*)d_in[8];
    float* out = (float*)d_out;

    int* wsi      = (int*)d_ws;
    ushort_t* wsu = (ushort_t*)d_ws;
    int* rowptr   = wsi + IOFF_ROWPTR;
    int* eidx     = wsi + IOFF_EIDX;
    int* bbase    = wsi + IOFF_BBASE;
    int* bcnt     = wsi + IOFF_BCNT;
    ushort_t* wT    = wsu + UOFF_WT;
    ushort_t* featb = wsu + UOFF_FEATB;
    ushort_t* agg1b = wsu + UOFF_AGG1B;
    ushort_t* h1b   = wsu + UOFF_H1B;
    ushort_t* p2b   = wsu + UOFF_P2B;
    uint_t* bucket  = (uint_t*)(wsu + UOFF_H1B);  // aliased: dead before gemm1 writes h1b

    // zero bcnt (196 ints)
    hipMemsetAsync(bcnt, 0, NB * sizeof(int), stream);

    // weight transpose+convert; feat -> bf16 (independent of CSR build)
    wprep_kernel<<<(49152 + 255) / 256, 256, 0, stream>>>(Ws1, Wn1, Ws2, Wn2, wT);
    cvt_kernel<<<(N_NODES * 128 / 4 + 255) / 256, 256, 0, stream>>>(feat, featb, N_NODES * 128 / 4);

    // ---- bucketed CSR build (hist/scans folded into fill_bucket) ----
    bucket_kernel<<<NBLK_BUCKET, 256, 0, stream>>>(src, dst, bucket, bcnt);
    scan196<<<1, 256, 0, stream>>>(bcnt, bbase, rowptr);
    fill_bucket<<<NB, 512, 0, stream>>>(bucket, bcnt, bbase, rowptr, eidx);

    // ---- layer 1 ----
    gather128_kernel<<<(N_NODES + 3) / 4, 256, 0, stream>>>(rowptr, eidx, featb, agg1b);
    gemm1_mfma<<<(N_NODES + 127) / 128, 256, 0, stream>>>(featb, agg1b, wT, b1, h1b);

    // ---- layer 2 (fused dual GEMM, aggregate-after-matmul) ----
    gemm2_mfma<<<(N_NODES + 127) / 128, 256, 0, stream>>>(h1b, wT + 32768, b2, p2b, out);
    gather64_add_kernel<<<(N_NODES + 3) / 4, 256, 0, stream>>>(rowptr, eidx, p2b, out);
}

// Round 9
// 224.690 us; speedup vs baseline: 1.7235x; 1.1884x over previous
//
#include <hip/hip_runtime.h>

#define N_NODES 50000
#define N_EDGES 800000
// IN=128, HID=128, OUT=64

typedef unsigned short ushort_t;
typedef unsigned int uint_t;
typedef __attribute__((ext_vector_type(8))) short bf16x8;
typedef __attribute__((ext_vector_type(4))) float f32x4;

#define NB 196        // buckets: dst>>8 (256 nodes per bucket)
#define BCAP 6144     // per-bucket capacity (avg 4082, +safety)
#define SDEPTH 16     // LDS staging depth per bucket
#define EPB 1024      // edges per bucket_kernel block
#define NBLK_BUCKET ((N_EDGES + EPB - 1) / EPB)

// ---------------- workspace layout ----------------
// int region (int offsets; bytes = x4):
//   rowptr  [50001]   @ 100000   (bytes 400000..600004)
//   eidx    [800000]  @ 150016   (bytes 600064..3800064)
//   bbase   [256]     @ 950016   (bytes 3800064..3801088)
//   bcnt    [196]     @ 950528   (bytes 3802112..3802896)
// bf16 region (ushort offsets; bytes = x2):
//   wT    [49152]     @ 1920000  (bytes 3840000..3938304)
//   featb [50000*128] @ 2000000  (bytes 4000000..16800000)
//   agg1b [50000*128] @ 8400000  (bytes 16800000..29600000)
//   h1b   [50000*128] @ 14800000 (bytes 29600000..42400000; bucket u32[196*6144]=4.8MB aliased pre-gemm1)
//   p2b   [50000*64]  @ 21200000 (bytes 42400000..48800000)
#define IOFF_ROWPTR  100000
#define IOFF_EIDX    150016
#define IOFF_BBASE   950016
#define IOFF_BCNT    950528
#define UOFF_WT      1920000
#define UOFF_FEATB   2000000
#define UOFF_AGG1B   8400000
#define UOFF_H1B     14800000
#define UOFF_P2B     21200000

__device__ __forceinline__ float bf2f(uint_t u) {
    return __uint_as_float(u << 16);
}
__device__ __forceinline__ uint_t f2bf(float f) {
    uint_t x = __float_as_uint(f);
    return (x + 0x7FFFu + ((x >> 16) & 1u)) >> 16;  // RNE
}

// ---- bucketed CSR build ----
__global__ __launch_bounds__(256) void bucket_kernel(const int* __restrict__ src,
                                                     const int* __restrict__ dst,
                                                     uint_t* __restrict__ bucket,
                                                     int* __restrict__ bcnt) {
    __shared__ uint_t stage[NB][SDEPTH];
    __shared__ int lcnt[NB];
    __shared__ int gbase[NB];
    int tid = threadIdx.x;
    for (int i = tid; i < NB; i += 256) lcnt[i] = 0;
    __syncthreads();
    int e0 = blockIdx.x * EPB;
#pragma unroll
    for (int it = 0; it < EPB / 256; ++it) {
        int e = e0 + it * 256 + tid;
        if (e < N_EDGES) {
            int d = dst[e], s = src[e];
            uint_t v = ((uint_t)d << 16) | (uint_t)s;
            int b = d >> 8;
            int slot = atomicAdd(&lcnt[b], 1);
            if (slot < SDEPTH) {
                stage[b][slot] = v;
            } else {  // rare overflow: direct reservation
                int p = atomicAdd(&bcnt[b], 1);
                bucket[(long)b * BCAP + p] = v;
            }
        }
    }
    __syncthreads();
    if (tid < NB) {
        int n = min(lcnt[tid], SDEPTH);
        gbase[tid] = (n > 0) ? atomicAdd(&bcnt[tid], n) : 0;
    }
    __syncthreads();
    for (int s = tid; s < NB * SDEPTH; s += 256) {
        int b = s >> 4, i = s & (SDEPTH - 1);
        if (i < min(lcnt[b], SDEPTH))
            bucket[(long)b * BCAP + gbase[b] + i] = stage[b][i];
    }
}

__global__ __launch_bounds__(256) void scan196(const int* __restrict__ bcnt,
                                               int* __restrict__ bbase,
                                               int* __restrict__ rowptr) {
    __shared__ int sh[256];
    int tid = threadIdx.x;
    int v = (tid < NB) ? bcnt[tid] : 0;
    sh[tid] = v;
    __syncthreads();
    for (int off = 1; off < 256; off <<= 1) {
        int t = (tid >= off) ? sh[tid - off] : 0;
        __syncthreads();
        sh[tid] += t;
        __syncthreads();
    }
    if (tid < NB) bbase[tid] = sh[tid] - v;
    if (tid == NB - 1) rowptr[N_NODES] = sh[tid];
}

__global__ __launch_bounds__(512) void fill_bucket(const uint_t* __restrict__ bucket,
                                                   const int* __restrict__ bcnt,
                                                   const int* __restrict__ bbase,
                                                   int* __restrict__ rowptr,
                                                   int* __restrict__ eidx) {
    __shared__ int hist[256];
    __shared__ int excl[256];
    __shared__ int fp[256];
    int b = blockIdx.x, tid = threadIdx.x;
    if (tid < 256) { hist[tid] = 0; fp[tid] = 0; }
    __syncthreads();
    int n = bcnt[b];
    int base = bbase[b];
    int nodebase = b << 8;
    const uint_t* bk = bucket + (long)b * BCAP;
    for (int i = tid; i < n; i += 512) {
        int d = (int)(bk[i] >> 16) - nodebase;
        atomicAdd(&hist[d], 1);
    }
    __syncthreads();
    int v = 0;
    if (tid < 256) { v = hist[tid]; excl[tid] = v; }
    __syncthreads();
    for (int off = 1; off < 256; off <<= 1) {
        int t = 0;
        if (tid < 256 && tid >= off) t = excl[tid - off];
        __syncthreads();
        if (tid < 256) excl[tid] += t;
        __syncthreads();
    }
    if (tid < 256) {
        excl[tid] -= v;
        int node = nodebase + tid;
        if (node < N_NODES) rowptr[node] = base + excl[tid];
    }
    __syncthreads();
    for (int i = tid; i < n; i += 512) {
        uint_t vv = bk[i];
        int d = (int)(vv >> 16) - nodebase;
        int off = atomicAdd(&fp[d], 1);
        eidx[base + excl[d] + off] = (int)(vv & 0xFFFFu);
    }
}

// f32 -> bf16, 4 floats/thread
__global__ __launch_bounds__(256) void cvt_kernel(const float* __restrict__ x,
                                                  ushort_t* __restrict__ y, int n4) {
    int i = blockIdx.x * 256 + threadIdx.x;
    if (i >= n4) return;
    float4 v = ((const float4*)x)[i];
    uint2 o;
    o.x = f2bf(v.x) | (f2bf(v.y) << 16);
    o.y = f2bf(v.z) | (f2bf(v.w) << 16);
    ((uint2*)y)[i] = o;
}

// transpose+convert all 4 weight mats into wT (bf16)
__global__ __launch_bounds__(256) void wprep_kernel(const float* __restrict__ Ws1,
                                                    const float* __restrict__ Wn1,
                                                    const float* __restrict__ Ws2,
                                                    const float* __restrict__ Wn2,
                                                    ushort_t* __restrict__ wT) {
    int i = blockIdx.x * 256 + threadIdx.x;
    if (i >= 49152) return;
    float v;
    if (i < 16384) {
        int n = i >> 7, k = i & 127;
        v = Ws1[k * 128 + n];
    } else if (i < 32768) {
        int j = i - 16384, n = j >> 7, k = j & 127;
        v = Wn1[k * 128 + n];
    } else if (i < 40960) {
        int j = i - 32768, n = j >> 7, k = j & 127;
        v = Wn2[k * 64 + n];
    } else {
        int j = i - 40960, n = j >> 7, k = j & 127;
        v = Ws2[k * 64 + n];
    }
    wT[i] = (ushort_t)f2bf(v);
}

// one wave per node; 16 lanes cover one 256B row (16B/lane), 4 edges per wave-load.
// q = lane>>4 is the edge sub-slot; final reduce across sub-slots via shfl_xor.
__global__ __launch_bounds__(256) void gather128_kernel(const int* __restrict__ rowptr,
                                                        const int* __restrict__ eidx,
                                                        const ushort_t* __restrict__ xb,
                                                        ushort_t* __restrict__ aggb) {
    int node = blockIdx.x * 4 + (threadIdx.x >> 6);
    int lane = threadIdx.x & 63;
    if (node >= N_NODES) return;
    int q = lane >> 4;    // edge slot 0..3
    int sl = lane & 15;   // col group: cols sl*8 .. sl*8+7
    int beg = rowptr[node], end = rowptr[node + 1];
    float acc[8];
#pragma unroll
    for (int j = 0; j < 8; ++j) acc[j] = 0.f;

    int e = beg;
    for (; e + 7 < end; e += 8) {
        int sA = eidx[e + q];
        int sB = eidx[e + 4 + q];
        uint4 vA = *(const uint4*)(xb + (long)sA * 128 + sl * 8);
        uint4 vB = *(const uint4*)(xb + (long)sB * 128 + sl * 8);
        acc[0] += bf2f(vA.x & 0xffffu); acc[1] += bf2f(vA.x >> 16);
        acc[2] += bf2f(vA.y & 0xffffu); acc[3] += bf2f(vA.y >> 16);
        acc[4] += bf2f(vA.z & 0xffffu); acc[5] += bf2f(vA.z >> 16);
        acc[6] += bf2f(vA.w & 0xffffu); acc[7] += bf2f(vA.w >> 16);
        acc[0] += bf2f(vB.x & 0xffffu); acc[1] += bf2f(vB.x >> 16);
        acc[2] += bf2f(vB.y & 0xffffu); acc[3] += bf2f(vB.y >> 16);
        acc[4] += bf2f(vB.z & 0xffffu); acc[5] += bf2f(vB.z >> 16);
        acc[6] += bf2f(vB.w & 0xffffu); acc[7] += bf2f(vB.w >> 16);
    }
    for (; e + 3 < end; e += 4) {
        int s = eidx[e + q];
        uint4 v = *(const uint4*)(xb + (long)s * 128 + sl * 8);
        acc[0] += bf2f(v.x & 0xffffu); acc[1] += bf2f(v.x >> 16);
        acc[2] += bf2f(v.y & 0xffffu); acc[3] += bf2f(v.y >> 16);
        acc[4] += bf2f(v.z & 0xffffu); acc[5] += bf2f(v.z >> 16);
        acc[6] += bf2f(v.w & 0xffffu); acc[7] += bf2f(v.w >> 16);
    }
    if (e + q < end) {  // tail: 1..3 edges, slots q < remainder
        int s = eidx[e + q];
        uint4 v = *(const uint4*)(xb + (long)s * 128 + sl * 8);
        acc[0] += bf2f(v.x & 0xffffu); acc[1] += bf2f(v.x >> 16);
        acc[2] += bf2f(v.y & 0xffffu); acc[3] += bf2f(v.y >> 16);
        acc[4] += bf2f(v.z & 0xffffu); acc[5] += bf2f(v.z >> 16);
        acc[6] += bf2f(v.w & 0xffffu); acc[7] += bf2f(v.w >> 16);
    }
#pragma unroll
    for (int j = 0; j < 8; ++j) {
        acc[j] += __shfl_xor(acc[j], 16);
        acc[j] += __shfl_xor(acc[j], 32);
    }
    float inv = (end > beg) ? 1.0f / (float)(end - beg) : 0.f;
    if (lane < 16) {
        uint4 o;
        o.x = f2bf(acc[0] * inv) | (f2bf(acc[1] * inv) << 16);
        o.y = f2bf(acc[2] * inv) | (f2bf(acc[3] * inv) << 16);
        o.z = f2bf(acc[4] * inv) | (f2bf(acc[5] * inv) << 16);
        o.w = f2bf(acc[6] * inv) | (f2bf(acc[7] * inv) << 16);
        *(uint4*)(aggb + (long)node * 128 + sl * 8) = o;
    }
}

// one wave per node; 16 lanes cover one 128B row (8B/lane), 4 edges per wave-load.
__global__ __launch_bounds__(256) void gather64_add_kernel(const int* __restrict__ rowptr,
                                                           const int* __restrict__ eidx,
                                                           const ushort_t* __restrict__ p2b,
                                                           float* __restrict__ out) {
    int node = blockIdx.x * 4 + (threadIdx.x >> 6);
    int lane = threadIdx.x & 63;
    if (node >= N_NODES) return;
    int q = lane >> 4;    // edge slot 0..3
    int sl = lane & 15;   // col group: cols sl*4 .. sl*4+3
    int beg = rowptr[node], end = rowptr[node + 1];
    float acc[4];
#pragma unroll
    for (int j = 0; j < 4; ++j) acc[j] = 0.f;

    int e = beg;
    for (; e + 7 < end; e += 8) {
        int sA = eidx[e + q];
        int sB = eidx[e + 4 + q];
        uint2 vA = *(const uint2*)(p2b + (long)sA * 64 + sl * 4);
        uint2 vB = *(const uint2*)(p2b + (long)sB * 64 + sl * 4);
        acc[0] += bf2f(vA.x & 0xffffu); acc[1] += bf2f(vA.x >> 16);
        acc[2] += bf2f(vA.y & 0xffffu); acc[3] += bf2f(vA.y >> 16);
        acc[0] += bf2f(vB.x & 0xffffu); acc[1] += bf2f(vB.x >> 16);
        acc[2] += bf2f(vB.y & 0xffffu); acc[3] += bf2f(vB.y >> 16);
    }
    for (; e + 3 < end; e += 4) {
        int s = eidx[e + q];
        uint2 v = *(const uint2*)(p2b + (long)s * 64 + sl * 4);
        acc[0] += bf2f(v.x & 0xffffu); acc[1] += bf2f(v.x >> 16);
        acc[2] += bf2f(v.y & 0xffffu); acc[3] += bf2f(v.y >> 16);
    }
    if (e + q < end) {
        int s = eidx[e + q];
        uint2 v = *(const uint2*)(p2b + (long)s * 64 + sl * 4);
        acc[0] += bf2f(v.x & 0xffffu); acc[1] += bf2f(v.x >> 16);
        acc[2] += bf2f(v.y & 0xffffu); acc[3] += bf2f(v.y >> 16);
    }
#pragma unroll
    for (int j = 0; j < 4; ++j) {
        acc[j] += __shfl_xor(acc[j], 16);
        acc[j] += __shfl_xor(acc[j], 32);
    }
    float inv = (end > beg) ? 1.0f / (float)(end - beg) : 0.f;
    if (lane < 16) {
        float4* po = (float4*)(out + (long)node * 64 + sl * 4);
        float4 o = *po;
        o.x += acc[0] * inv;
        o.y += acc[1] * inv;
        o.z += acc[2] * inv;
        o.w += acc[3] * inv;
        *po = o;
    }
}

// ---------------- MFMA GEMMs (no LDS; frags straight from global) ----------------
// A frag (16x16x32 bf16): row = lane&15, k = (lane>>4)*8 + e  -> 16B contiguous
// B frag: col = lane&15, same k                               -> 16B contiguous in W^T
// D frag: col = lane&15, row = (lane>>4)*4 + reg

__global__ __launch_bounds__(256) void gemm1_mfma(const ushort_t* __restrict__ featb,
                                                  const ushort_t* __restrict__ agg1b,
                                                  const ushort_t* __restrict__ wT,
                                                  const float* __restrict__ b,
                                                  ushort_t* __restrict__ h1b) {
    int lane = threadIdx.x & 63;
    int w = threadIdx.x >> 6;
    int mbase = blockIdx.x * 128 + w * 32;
    int lr = lane & 15;
    int kg = (lane >> 4) * 8;

    long r0 = mbase + lr;
    long r1 = mbase + 16 + lr;
    if (r0 > N_NODES - 1) r0 = N_NODES - 1;
    if (r1 > N_NODES - 1) r1 = N_NODES - 1;

    f32x4 acc[2][8];
#pragma unroll
    for (int mt = 0; mt < 2; ++mt)
#pragma unroll
        for (int nt = 0; nt < 8; ++nt) acc[mt][nt] = (f32x4){0.f, 0.f, 0.f, 0.f};

#pragma unroll
    for (int pass = 0; pass < 2; ++pass) {
        const ushort_t* a = pass ? agg1b : featb;
        const ushort_t* wt = wT + pass * (128 * 128);
#pragma unroll
        for (int ks = 0; ks < 4; ++ks) {
            int k = ks * 32 + kg;
            bf16x8 a0 = *(const bf16x8*)(a + r0 * 128 + k);
            bf16x8 a1 = *(const bf16x8*)(a + r1 * 128 + k);
#pragma unroll
            for (int nt = 0; nt < 8; ++nt) {
                bf16x8 bb = *(const bf16x8*)(wt + (nt * 16 + lr) * 128 + k);
                acc[0][nt] = __builtin_amdgcn_mfma_f32_16x16x32_bf16(a0, bb, acc[0][nt], 0, 0, 0);
                acc[1][nt] = __builtin_amdgcn_mfma_f32_16x16x32_bf16(a1, bb, acc[1][nt], 0, 0, 0);
            }
        }
    }

    int drow = (lane >> 4) * 4;
#pragma unroll
    for (int nt = 0; nt < 8; ++nt) {
        int n = nt * 16 + lr;
        float bias = b[n];
#pragma unroll
        for (int mt = 0; mt < 2; ++mt) {
#pragma unroll
            for (int r = 0; r < 4; ++r) {
                int row = mbase + mt * 16 + drow + r;
                if (row < N_NODES) {
                    float v = fmaxf(acc[mt][nt][r] + bias, 0.f);
                    h1b[(long)row * 128 + n] = (ushort_t)f2bf(v);
                }
            }
        }
    }
}

// fused layer-2: p2b = bf16(h1b@Wn2); out = h1b@Ws2 + b2  (A-frags shared)
__global__ __launch_bounds__(256) void gemm2_mfma(const ushort_t* __restrict__ h1b,
                                                  const ushort_t* __restrict__ wT2,  // [WnT2 | WsT2]
                                                  const float* __restrict__ b2,
                                                  ushort_t* __restrict__ p2b,
                                                  float* __restrict__ out) {
    int lane = threadIdx.x & 63;
    int w = threadIdx.x >> 6;
    int mbase = blockIdx.x * 128 + w * 32;
    int lr = lane & 15;
    int kg = (lane >> 4) * 8;

    long r0 = mbase + lr;
    long r1 = mbase + 16 + lr;
    if (r0 > N_NODES - 1) r0 = N_NODES - 1;
    if (r1 > N_NODES - 1) r1 = N_NODES - 1;

    f32x4 accP[2][4], accO[2][4];
#pragma unroll
    for (int mt = 0; mt < 2; ++mt)
#pragma unroll
        for (int nt = 0; nt < 4; ++nt) {
            accP[mt][nt] = (f32x4){0.f, 0.f, 0.f, 0.f};
            accO[mt][nt] = (f32x4){0.f, 0.f, 0.f, 0.f};
        }

#pragma unroll
    for (int ks = 0; ks < 4; ++ks) {
        int k = ks * 32 + kg;
        bf16x8 a0 = *(const bf16x8*)(h1b + r0 * 128 + k);
        bf16x8 a1 = *(const bf16x8*)(h1b + r1 * 128 + k);
#pragma unroll
        for (int nt = 0; nt < 4; ++nt) {
            bf16x8 bn = *(const bf16x8*)(wT2 + (nt * 16 + lr) * 128 + k);
            bf16x8 bs = *(const bf16x8*)(wT2 + 8192 + (nt * 16 + lr) * 128 + k);
            accP[0][nt] = __builtin_amdgcn_mfma_f32_16x16x32_bf16(a0, bn, accP[0][nt], 0, 0, 0);
            accP[1][nt] = __builtin_amdgcn_mfma_f32_16x16x32_bf16(a1, bn, accP[1][nt], 0, 0, 0);
            accO[0][nt] = __builtin_amdgcn_mfma_f32_16x16x32_bf16(a0, bs, accO[0][nt], 0, 0, 0);
            accO[1][nt] = __builtin_amdgcn_mfma_f32_16x16x32_bf16(a1, bs, accO[1][nt], 0, 0, 0);
        }
    }

    int drow = (lane >> 4) * 4;
#pragma unroll
    for (int nt = 0; nt < 4; ++nt) {
        int n = nt * 16 + lr;
        float bias = b2[n];
#pragma unroll
        for (int mt = 0; mt < 2; ++mt) {
#pragma unroll
            for (int r = 0; r < 4; ++r) {
                int row = mbase + mt * 16 + drow + r;
                if (row < N_NODES) {
                    p2b[(long)row * 64 + n] = (ushort_t)f2bf(accP[mt][nt][r]);
                    out[(long)row * 64 + n] = accO[mt][nt][r] + bias;
                }
            }
        }
    }
}

extern "C" void kernel_launch(void* const* d_in, const int* in_sizes, int n_in,
                              void* d_out, int out_size, void* d_ws, size_t ws_size,
                              hipStream_t stream) {
    const float* feat = (const float*)d_in[0];
    const int* src    = (const int*)d_in[1];
    const int* dst    = (const int*)d_in[2];
    const float* Ws1  = (const float*)d_in[3];
    const float* Wn1  = (const float*)d_in[4];
    const float* b1   = (const float*)d_in[5];
    const float* Ws2  = (const float*)d_in[6];
    const float* Wn2  = (const float*)d_in[7];
    const float* b2   = (const float*)d_in[8];
    float* out = (float*)d_out;

    int* wsi      = (int*)d_ws;
    ushort_t* wsu = (ushort_t*)d_ws;
    int* rowptr   = wsi + IOFF_ROWPTR;
    int* eidx     = wsi + IOFF_EIDX;
    int* bbase    = wsi + IOFF_BBASE;
    int* bcnt     = wsi + IOFF_BCNT;
    ushort_t* wT    = wsu + UOFF_WT;
    ushort_t* featb = wsu + UOFF_FEATB;
    ushort_t* agg1b = wsu + UOFF_AGG1B;
    ushort_t* h1b   = wsu + UOFF_H1B;
    ushort_t* p2b   = wsu + UOFF_P2B;
    uint_t* bucket  = (uint_t*)(wsu + UOFF_H1B);  // aliased: dead before gemm1 writes h1b

    // zero bcnt (196 ints)
    hipMemsetAsync(bcnt, 0, NB * sizeof(int), stream);

    // weight transpose+convert; feat -> bf16 (independent of CSR build)
    wprep_kernel<<<(49152 + 255) / 256, 256, 0, stream>>>(Ws1, Wn1, Ws2, Wn2, wT);
    cvt_kernel<<<(N_NODES * 128 / 4 + 255) / 256, 256, 0, stream>>>(feat, featb, N_NODES * 128 / 4);

    // ---- bucketed CSR build ----
    bucket_kernel<<<NBLK_BUCKET, 256, 0, stream>>>(src, dst, bucket, bcnt);
    scan196<<<1, 256, 0, stream>>>(bcnt, bbase, rowptr);
    fill_bucket<<<NB, 512, 0, stream>>>(bucket, bcnt, bbase, rowptr, eidx);

    // ---- layer 1 ----
    gather128_kernel<<<(N_NODES + 3) / 4, 256, 0, stream>>>(rowptr, eidx, featb, agg1b);
    gemm1_mfma<<<(N_NODES + 127) / 128, 256, 0, stream>>>(featb, agg1b, wT, b1, h1b);

    // ---- layer 2 (fused dual GEMM, aggregate-after-matmul) ----
    gemm2_mfma<<<(N_NODES + 127) / 128, 256, 0, stream>>>(h1b, wT + 32768, b2, p2b, out);
    gather64_add_kernel<<<(N_NODES + 3) / 4, 256, 0, stream>>>(rowptr, eidx, p2b, out);
}

// Round 10
// 220.662 us; speedup vs baseline: 1.7550x; 1.0183x over previous
//
#include <hip/hip_runtime.h>

#define N_NODES 50000
#define N_EDGES 800000
// IN=128, HID=128, OUT=64

typedef unsigned short ushort_t;
typedef unsigned int uint_t;
typedef __attribute__((ext_vector_type(8))) short bf16x8;
typedef __attribute__((ext_vector_type(4))) float f32x4;

#define NB 196        // buckets: dst>>8 (256 nodes per bucket)
#define BCAP 6144     // per-bucket capacity (avg 4082, +safety)
#define SDEPTH 16     // LDS staging depth per bucket
#define EPB 1024      // edges per bucket_kernel block
#define NBLK_BUCKET ((N_EDGES + EPB - 1) / EPB)
#define NCVT4 (N_NODES * 128 / 4)   // 1,600,000 float4 groups for feat cvt

// ---------------- workspace layout ----------------
// int region (int offsets; bytes = x4):
//   rowptr  [50001]   @ 100000   (bytes 400000..600004)
//   eidx    [800000]  @ 150016   (bytes 600064..3800064)
//   bbase   [256]     @ 950016   (bytes 3800064..3801088)
//   bcnt    [196]     @ 950528   (bytes 3802112..3802896)
// bf16 region (ushort offsets; bytes = x2):
//   wT    [49152]     @ 1920000  (bytes 3840000..3938304)
//   featb [50000*128] @ 2000000  (bytes 4000000..16800000)
//   agg1b [50000*128] @ 8400000  (bytes 16800000..29600000)
//   h1b   [50000*128] @ 14800000 (bytes 29600000..42400000; bucket u32[196*6144]=4.8MB aliased pre-gemm1)
//   p2b   [50000*64]  @ 21200000 (bytes 42400000..48800000)
#define IOFF_ROWPTR  100000
#define IOFF_EIDX    150016
#define IOFF_BBASE   950016
#define IOFF_BCNT    950528
#define UOFF_WT      1920000
#define UOFF_FEATB   2000000
#define UOFF_AGG1B   8400000
#define UOFF_H1B     14800000
#define UOFF_P2B     21200000

__device__ __forceinline__ float bf2f(uint_t u) {
    return __uint_as_float(u << 16);
}
__device__ __forceinline__ uint_t f2bf(float f) {
    uint_t x = __float_as_uint(f);
    return (x + 0x7FFFu + ((x >> 16) & 1u)) >> 16;  // RNE
}

// ---- bucketed CSR build ----
__global__ __launch_bounds__(256) void bucket_kernel(const int* __restrict__ src,
                                                     const int* __restrict__ dst,
                                                     uint_t* __restrict__ bucket,
                                                     int* __restrict__ bcnt) {
    __shared__ uint_t stage[NB][SDEPTH];
    __shared__ int lcnt[NB];
    __shared__ int gbase[NB];
    int tid = threadIdx.x;
    for (int i = tid; i < NB; i += 256) lcnt[i] = 0;
    __syncthreads();
    int e0 = blockIdx.x * EPB;
#pragma unroll
    for (int it = 0; it < EPB / 256; ++it) {
        int e = e0 + it * 256 + tid;
        if (e < N_EDGES) {
            int d = dst[e], s = src[e];
            uint_t v = ((uint_t)d << 16) | (uint_t)s;
            int b = d >> 8;
            int slot = atomicAdd(&lcnt[b], 1);
            if (slot < SDEPTH) {
                stage[b][slot] = v;
            } else {  // rare overflow: direct reservation
                int p = atomicAdd(&bcnt[b], 1);
                bucket[(long)b * BCAP + p] = v;
            }
        }
    }
    __syncthreads();
    if (tid < NB) {
        int n = min(lcnt[tid], SDEPTH);
        gbase[tid] = (n > 0) ? atomicAdd(&bcnt[tid], n) : 0;
    }
    __syncthreads();
    for (int s = tid; s < NB * SDEPTH; s += 256) {
        int b = s >> 4, i = s & (SDEPTH - 1);
        if (i < min(lcnt[b], SDEPTH))
            bucket[(long)b * BCAP + gbase[b] + i] = stage[b][i];
    }
}

__global__ __launch_bounds__(256) void scan196(const int* __restrict__ bcnt,
                                               int* __restrict__ bbase,
                                               int* __restrict__ rowptr) {
    __shared__ int sh[256];
    int tid = threadIdx.x;
    int v = (tid < NB) ? bcnt[tid] : 0;
    sh[tid] = v;
    __syncthreads();
    for (int off = 1; off < 256; off <<= 1) {
        int t = (tid >= off) ? sh[tid - off] : 0;
        __syncthreads();
        sh[tid] += t;
        __syncthreads();
    }
    if (tid < NB) bbase[tid] = sh[tid] - v;
    if (tid == NB - 1) rowptr[N_NODES] = sh[tid];
}

__global__ __launch_bounds__(1024) void fill_bucket(const uint_t* __restrict__ bucket,
                                                    const int* __restrict__ bcnt,
                                                    const int* __restrict__ bbase,
                                                    int* __restrict__ rowptr,
                                                    int* __restrict__ eidx) {
    __shared__ int hist[256];
    __shared__ int excl[256];
    __shared__ int fp[256];
    int b = blockIdx.x, tid = threadIdx.x;
    if (tid < 256) { hist[tid] = 0; fp[tid] = 0; }
    __syncthreads();
    int n = bcnt[b];
    int base = bbase[b];
    int nodebase = b << 8;
    const uint_t* bk = bucket + (long)b * BCAP;
    for (int i = tid; i < n; i += 1024) {
        int d = (int)(bk[i] >> 16) - nodebase;
        atomicAdd(&hist[d], 1);
    }
    __syncthreads();
    int v = 0;
    if (tid < 256) { v = hist[tid]; excl[tid] = v; }
    __syncthreads();
    for (int off = 1; off < 256; off <<= 1) {
        int t = 0;
        if (tid < 256 && tid >= off) t = excl[tid - off];
        __syncthreads();
        if (tid < 256) excl[tid] += t;
        __syncthreads();
    }
    if (tid < 256) {
        excl[tid] -= v;
        int node = nodebase + tid;
        if (node < N_NODES) rowptr[node] = base + excl[tid];
    }
    __syncthreads();
    for (int i = tid; i < n; i += 1024) {
        uint_t vv = bk[i];
        int d = (int)(vv >> 16) - nodebase;
        int off = atomicAdd(&fp[d], 1);
        eidx[base + excl[d] + off] = (int)(vv & 0xFFFFu);
    }
}

// fused prep: feat f32->bf16 (first NCVT4 groups) + weight transpose/convert (last 49152)
__global__ __launch_bounds__(256) void prep_kernel(const float* __restrict__ feat,
                                                   const float* __restrict__ Ws1,
                                                   const float* __restrict__ Wn1,
                                                   const float* __restrict__ Ws2,
                                                   const float* __restrict__ Wn2,
                                                   ushort_t* __restrict__ featb,
                                                   ushort_t* __restrict__ wT) {
    int i = blockIdx.x * 256 + threadIdx.x;
    if (i < NCVT4) {
        float4 v = ((const float4*)feat)[i];
        uint2 o;
        o.x = f2bf(v.x) | (f2bf(v.y) << 16);
        o.y = f2bf(v.z) | (f2bf(v.w) << 16);
        ((uint2*)featb)[i] = o;
        return;
    }
    int j = i - NCVT4;
    if (j >= 49152) return;
    float v;
    if (j < 16384) {
        int n = j >> 7, k = j & 127;
        v = Ws1[k * 128 + n];
    } else if (j < 32768) {
        int jj = j - 16384, n = jj >> 7, k = jj & 127;
        v = Wn1[k * 128 + n];
    } else if (j < 40960) {
        int jj = j - 32768, n = jj >> 7, k = jj & 127;
        v = Wn2[k * 64 + n];
    } else {
        int jj = j - 40960, n = jj >> 7, k = jj & 127;
        v = Ws2[k * 64 + n];
    }
    wT[j] = (ushort_t)f2bf(v);
}

// one wave per node; 16 lanes cover one 256B row (16B/lane), 4 edges per wave-load.
// 16-edge unroll: 4 independent row-loads in flight per lane.
__global__ __launch_bounds__(256) void gather128_kernel(const int* __restrict__ rowptr,
                                                        const int* __restrict__ eidx,
                                                        const ushort_t* __restrict__ xb,
                                                        ushort_t* __restrict__ aggb) {
    int node = blockIdx.x * 4 + (threadIdx.x >> 6);
    int lane = threadIdx.x & 63;
    if (node >= N_NODES) return;
    int q = lane >> 4;    // edge slot 0..3
    int sl = lane & 15;   // col group: cols sl*8 .. sl*8+7
    int beg = rowptr[node], end = rowptr[node + 1];
    float acc[8];
#pragma unroll
    for (int j = 0; j < 8; ++j) acc[j] = 0.f;

    int e = beg;
    for (; e + 15 < end; e += 16) {
        int s0 = eidx[e + q];
        int s1 = eidx[e + 4 + q];
        int s2 = eidx[e + 8 + q];
        int s3 = eidx[e + 12 + q];
        uint4 v0 = *(const uint4*)(xb + (long)s0 * 128 + sl * 8);
        uint4 v1 = *(const uint4*)(xb + (long)s1 * 128 + sl * 8);
        uint4 v2 = *(const uint4*)(xb + (long)s2 * 128 + sl * 8);
        uint4 v3 = *(const uint4*)(xb + (long)s3 * 128 + sl * 8);
        acc[0] += bf2f(v0.x & 0xffffu); acc[1] += bf2f(v0.x >> 16);
        acc[2] += bf2f(v0.y & 0xffffu); acc[3] += bf2f(v0.y >> 16);
        acc[4] += bf2f(v0.z & 0xffffu); acc[5] += bf2f(v0.z >> 16);
        acc[6] += bf2f(v0.w & 0xffffu); acc[7] += bf2f(v0.w >> 16);
        acc[0] += bf2f(v1.x & 0xffffu); acc[1] += bf2f(v1.x >> 16);
        acc[2] += bf2f(v1.y & 0xffffu); acc[3] += bf2f(v1.y >> 16);
        acc[4] += bf2f(v1.z & 0xffffu); acc[5] += bf2f(v1.z >> 16);
        acc[6] += bf2f(v1.w & 0xffffu); acc[7] += bf2f(v1.w >> 16);
        acc[0] += bf2f(v2.x & 0xffffu); acc[1] += bf2f(v2.x >> 16);
        acc[2] += bf2f(v2.y & 0xffffu); acc[3] += bf2f(v2.y >> 16);
        acc[4] += bf2f(v2.z & 0xffffu); acc[5] += bf2f(v2.z >> 16);
        acc[6] += bf2f(v2.w & 0xffffu); acc[7] += bf2f(v2.w >> 16);
        acc[0] += bf2f(v3.x & 0xffffu); acc[1] += bf2f(v3.x >> 16);
        acc[2] += bf2f(v3.y & 0xffffu); acc[3] += bf2f(v3.y >> 16);
        acc[4] += bf2f(v3.z & 0xffffu); acc[5] += bf2f(v3.z >> 16);
        acc[6] += bf2f(v3.w & 0xffffu); acc[7] += bf2f(v3.w >> 16);
    }
    for (; e + 3 < end; e += 4) {
        int s = eidx[e + q];
        uint4 v = *(const uint4*)(xb + (long)s * 128 + sl * 8);
        acc[0] += bf2f(v.x & 0xffffu); acc[1] += bf2f(v.x >> 16);
        acc[2] += bf2f(v.y & 0xffffu); acc[3] += bf2f(v.y >> 16);
        acc[4] += bf2f(v.z & 0xffffu); acc[5] += bf2f(v.z >> 16);
        acc[6] += bf2f(v.w & 0xffffu); acc[7] += bf2f(v.w >> 16);
    }
    if (e + q < end) {  // tail: 1..3 edges, slots q < remainder
        int s = eidx[e + q];
        uint4 v = *(const uint4*)(xb + (long)s * 128 + sl * 8);
        acc[0] += bf2f(v.x & 0xffffu); acc[1] += bf2f(v.x >> 16);
        acc[2] += bf2f(v.y & 0xffffu); acc[3] += bf2f(v.y >> 16);
        acc[4] += bf2f(v.z & 0xffffu); acc[5] += bf2f(v.z >> 16);
        acc[6] += bf2f(v.w & 0xffffu); acc[7] += bf2f(v.w >> 16);
    }
#pragma unroll
    for (int j = 0; j < 8; ++j) {
        acc[j] += __shfl_xor(acc[j], 16);
        acc[j] += __shfl_xor(acc[j], 32);
    }
    float inv = (end > beg) ? 1.0f / (float)(end - beg) : 0.f;
    if (lane < 16) {
        uint4 o;
        o.x = f2bf(acc[0] * inv) | (f2bf(acc[1] * inv) << 16);
        o.y = f2bf(acc[2] * inv) | (f2bf(acc[3] * inv) << 16);
        o.z = f2bf(acc[4] * inv) | (f2bf(acc[5] * inv) << 16);
        o.w = f2bf(acc[6] * inv) | (f2bf(acc[7] * inv) << 16);
        *(uint4*)(aggb + (long)node * 128 + sl * 8) = o;
    }
}

// one wave per node; 16 lanes cover one 128B row (8B/lane), 4 edges per wave-load.
// 16-edge unroll: 4 independent row-loads in flight per lane.
__global__ __launch_bounds__(256) void gather64_add_kernel(const int* __restrict__ rowptr,
                                                           const int* __restrict__ eidx,
                                                           const ushort_t* __restrict__ p2b,
                                                           float* __restrict__ out) {
    int node = blockIdx.x * 4 + (threadIdx.x >> 6);
    int lane = threadIdx.x & 63;
    if (node >= N_NODES) return;
    int q = lane >> 4;    // edge slot 0..3
    int sl = lane & 15;   // col group: cols sl*4 .. sl*4+3
    int beg = rowptr[node], end = rowptr[node + 1];
    float acc[4];
#pragma unroll
    for (int j = 0; j < 4; ++j) acc[j] = 0.f;

    int e = beg;
    for (; e + 15 < end; e += 16) {
        int s0 = eidx[e + q];
        int s1 = eidx[e + 4 + q];
        int s2 = eidx[e + 8 + q];
        int s3 = eidx[e + 12 + q];
        uint2 v0 = *(const uint2*)(p2b + (long)s0 * 64 + sl * 4);
        uint2 v1 = *(const uint2*)(p2b + (long)s1 * 64 + sl * 4);
        uint2 v2 = *(const uint2*)(p2b + (long)s2 * 64 + sl * 4);
        uint2 v3 = *(const uint2*)(p2b + (long)s3 * 64 + sl * 4);
        acc[0] += bf2f(v0.x & 0xffffu); acc[1] += bf2f(v0.x >> 16);
        acc[2] += bf2f(v0.y & 0xffffu); acc[3] += bf2f(v0.y >> 16);
        acc[0] += bf2f(v1.x & 0xffffu); acc[1] += bf2f(v1.x >> 16);
        acc[2] += bf2f(v1.y & 0xffffu); acc[3] += bf2f(v1.y >> 16);
        acc[0] += bf2f(v2.x & 0xffffu); acc[1] += bf2f(v2.x >> 16);
        acc[2] += bf2f(v2.y & 0xffffu); acc[3] += bf2f(v2.y >> 16);
        acc[0] += bf2f(v3.x & 0xffffu); acc[1] += bf2f(v3.x >> 16);
        acc[2] += bf2f(v3.y & 0xffffu); acc[3] += bf2f(v3.y >> 16);
    }
    for (; e + 3 < end; e += 4) {
        int s = eidx[e + q];
        uint2 v = *(const uint2*)(p2b + (long)s * 64 + sl * 4);
        acc[0] += bf2f(v.x & 0xffffu); acc[1] += bf2f(v.x >> 16);
        acc[2] += bf2f(v.y & 0xffffu); acc[3] += bf2f(v.y >> 16);
    }
    if (e + q < end) {
        int s = eidx[e + q];
        uint2 v = *(const uint2*)(p2b + (long)s * 64 + sl * 4);
        acc[0] += bf2f(v.x & 0xffffu); acc[1] += bf2f(v.x >> 16);
        acc[2] += bf2f(v.y & 0xffffu); acc[3] += bf2f(v.y >> 16);
    }
#pragma unroll
    for (int j = 0; j < 4; ++j) {
        acc[j] += __shfl_xor(acc[j], 16);
        acc[j] += __shfl_xor(acc[j], 32);
    }
    float inv = (end > beg) ? 1.0f / (float)(end - beg) : 0.f;
    if (lane < 16) {
        float4* po = (float4*)(out + (long)node * 64 + sl * 4);
        float4 o = *po;
        o.x += acc[0] * inv;
        o.y += acc[1] * inv;
        o.z += acc[2] * inv;
        o.w += acc[3] * inv;
        *po = o;
    }
}

// ---------------- MFMA GEMMs (no LDS; frags straight from global) ----------------
// A frag (16x16x32 bf16): row = lane&15, k = (lane>>4)*8 + e  -> 16B contiguous
// B frag: col = lane&15, same k                               -> 16B contiguous in W^T
// D frag: col = lane&15, row = (lane>>4)*4 + reg

__global__ __launch_bounds__(256) void gemm1_mfma(const ushort_t* __restrict__ featb,
                                                  const ushort_t* __restrict__ agg1b,
                                                  const ushort_t* __restrict__ wT,
                                                  const float* __restrict__ b,
                                                  ushort_t* __restrict__ h1b) {
    int lane = threadIdx.x & 63;
    int w = threadIdx.x >> 6;
    int mbase = blockIdx.x * 128 + w * 32;
    int lr = lane & 15;
    int kg = (lane >> 4) * 8;

    long r0 = mbase + lr;
    long r1 = mbase + 16 + lr;
    if (r0 > N_NODES - 1) r0 = N_NODES - 1;
    if (r1 > N_NODES - 1) r1 = N_NODES - 1;

    f32x4 acc[2][8];
#pragma unroll
    for (int mt = 0; mt < 2; ++mt)
#pragma unroll
        for (int nt = 0; nt < 8; ++nt) acc[mt][nt] = (f32x4){0.f, 0.f, 0.f, 0.f};

#pragma unroll
    for (int pass = 0; pass < 2; ++pass) {
        const ushort_t* a = pass ? agg1b : featb;
        const ushort_t* wt = wT + pass * (128 * 128);
#pragma unroll
        for (int ks = 0; ks < 4; ++ks) {
            int k = ks * 32 + kg;
            bf16x8 a0 = *(const bf16x8*)(a + r0 * 128 + k);
            bf16x8 a1 = *(const bf16x8*)(a + r1 * 128 + k);
#pragma unroll
            for (int nt = 0; nt < 8; ++nt) {
                bf16x8 bb = *(const bf16x8*)(wt + (nt * 16 + lr) * 128 + k);
                acc[0][nt] = __builtin_amdgcn_mfma_f32_16x16x32_bf16(a0, bb, acc[0][nt], 0, 0, 0);
                acc[1][nt] = __builtin_amdgcn_mfma_f32_16x16x32_bf16(a1, bb, acc[1][nt], 0, 0, 0);
            }
        }
    }

    int drow = (lane >> 4) * 4;
#pragma unroll
    for (int nt = 0; nt < 8; ++nt) {
        int n = nt * 16 + lr;
        float bias = b[n];
#pragma unroll
        for (int mt = 0; mt < 2; ++mt) {
#pragma unroll
            for (int r = 0; r < 4; ++r) {
                int row = mbase + mt * 16 + drow + r;
                if (row < N_NODES) {
                    float v = fmaxf(acc[mt][nt][r] + bias, 0.f);
                    h1b[(long)row * 128 + n] = (ushort_t)f2bf(v);
                }
            }
        }
    }
}

// fused layer-2: p2b = bf16(h1b@Wn2); out = h1b@Ws2 + b2  (A-frags shared)
__global__ __launch_bounds__(256) void gemm2_mfma(const ushort_t* __restrict__ h1b,
                                                  const ushort_t* __restrict__ wT2,  // [WnT2 | WsT2]
                                                  const float* __restrict__ b2,
                                                  ushort_t* __restrict__ p2b,
                                                  float* __restrict__ out) {
    int lane = threadIdx.x & 63;
    int w = threadIdx.x >> 6;
    int mbase = blockIdx.x * 128 + w * 32;
    int lr = lane & 15;
    int kg = (lane >> 4) * 8;

    long r0 = mbase + lr;
    long r1 = mbase + 16 + lr;
    if (r0 > N_NODES - 1) r0 = N_NODES - 1;
    if (r1 > N_NODES - 1) r1 = N_NODES - 1;

    f32x4 accP[2][4], accO[2][4];
#pragma unroll
    for (int mt = 0; mt < 2; ++mt)
#pragma unroll
        for (int nt = 0; nt < 4; ++nt) {
            accP[mt][nt] = (f32x4){0.f, 0.f, 0.f, 0.f};
            accO[mt][nt] = (f32x4){0.f, 0.f, 0.f, 0.f};
        }

#pragma unroll
    for (int ks = 0; ks < 4; ++ks) {
        int k = ks * 32 + kg;
        bf16x8 a0 = *(const bf16x8*)(h1b + r0 * 128 + k);
        bf16x8 a1 = *(const bf16x8*)(h1b + r1 * 128 + k);
#pragma unroll
        for (int nt = 0; nt < 4; ++nt) {
            bf16x8 bn = *(const bf16x8*)(wT2 + (nt * 16 + lr) * 128 + k);
            bf16x8 bs = *(const bf16x8*)(wT2 + 8192 + (nt * 16 + lr) * 128 + k);
            accP[0][nt] = __builtin_amdgcn_mfma_f32_16x16x32_bf16(a0, bn, accP[0][nt], 0, 0, 0);
            accP[1][nt] = __builtin_amdgcn_mfma_f32_16x16x32_bf16(a1, bn, accP[1][nt], 0, 0, 0);
            accO[0][nt] = __builtin_amdgcn_mfma_f32_16x16x32_bf16(a0, bs, accO[0][nt], 0, 0, 0);
            accO[1][nt] = __builtin_amdgcn_mfma_f32_16x16x32_bf16(a1, bs, accO[1][nt], 0, 0, 0);
        }
    }

    int drow = (lane >> 4) * 4;
#pragma unroll
    for (int nt = 0; nt < 4; ++nt) {
        int n = nt * 16 + lr;
        float bias = b2[n];
#pragma unroll
        for (int mt = 0; mt < 2; ++mt) {
#pragma unroll
            for (int r = 0; r < 4; ++r) {
                int row = mbase + mt * 16 + drow + r;
                if (row < N_NODES) {
                    p2b[(long)row * 64 + n] = (ushort_t)f2bf(accP[mt][nt][r]);
                    out[(long)row * 64 + n] = accO[mt][nt][r] + bias;
                }
            }
        }
    }
}

extern "C" void kernel_launch(void* const* d_in, const int* in_sizes, int n_in,
                              void* d_out, int out_size, void* d_ws, size_t ws_size,
                              hipStream_t stream) {
    const float* feat = (const float*)d_in[0];
    const int* src    = (const int*)d_in[1];
    const int* dst    = (const int*)d_in[2];
    const float* Ws1  = (const float*)d_in[3];
    const float* Wn1  = (const float*)d_in[4];
    const float* b1   = (const float*)d_in[5];
    const float* Ws2  = (const float*)d_in[6];
    const float* Wn2  = (const float*)d_in[7];
    const float* b2   = (const float*)d_in[8];
    float* out = (float*)d_out;

    int* wsi      = (int*)d_ws;
    ushort_t* wsu = (ushort_t*)d_ws;
    int* rowptr   = wsi + IOFF_ROWPTR;
    int* eidx     = wsi + IOFF_EIDX;
    int* bbase    = wsi + IOFF_BBASE;
    int* bcnt     = wsi + IOFF_BCNT;
    ushort_t* wT    = wsu + UOFF_WT;
    ushort_t* featb = wsu + UOFF_FEATB;
    ushort_t* agg1b = wsu + UOFF_AGG1B;
    ushort_t* h1b   = wsu + UOFF_H1B;
    ushort_t* p2b   = wsu + UOFF_P2B;
    uint_t* bucket  = (uint_t*)(wsu + UOFF_H1B);  // aliased: dead before gemm1 writes h1b

    // zero bcnt (196 ints)
    hipMemsetAsync(bcnt, 0, NB * sizeof(int), stream);

    // fused prep: feat -> bf16 + weight transpose/convert
    prep_kernel<<<(NCVT4 + 49152 + 255) / 256, 256, 0, stream>>>(feat, Ws1, Wn1, Ws2, Wn2, featb, wT);

    // ---- bucketed CSR build ----
    bucket_kernel<<<NBLK_BUCKET, 256, 0, stream>>>(src, dst, bucket, bcnt);
    scan196<<<1, 256, 0, stream>>>(bcnt, bbase, rowptr);
    fill_bucket<<<NB, 1024, 0, stream>>>(bucket, bcnt, bbase, rowptr, eidx);

    // ---- layer 1 ----
    gather128_kernel<<<(N_NODES + 3) / 4, 256, 0, stream>>>(rowptr, eidx, featb, agg1b);
    gemm1_mfma<<<(N_NODES + 127) / 128, 256, 0, stream>>>(featb, agg1b, wT, b1, h1b);

    // ---- layer 2 (fused dual GEMM, aggregate-after-matmul) ----
    gemm2_mfma<<<(N_NODES + 127) / 128, 256, 0, stream>>>(h1b, wT + 32768, b2, p2b, out);
    gather64_add_kernel<<<(N_NODES + 3) / 4, 256, 0, stream>>>(rowptr, eidx, p2b, out);
}

// Round 11
// 213.508 us; speedup vs baseline: 1.8138x; 1.0335x over previous
//
#include <hip/hip_runtime.h>

#define N_NODES 50000
#define N_EDGES 800000
// IN=128, HID=128, OUT=64

typedef unsigned short ushort_t;
typedef unsigned int uint_t;
typedef __attribute__((ext_vector_type(8))) short bf16x8;
typedef __attribute__((ext_vector_type(4))) float f32x4;

#define NB 196        // buckets: dst>>8 (256 nodes per bucket)
#define BCAP 6144     // per-bucket capacity (avg 4082, +safety)
#define SDEPTH 32     // LDS staging depth per bucket
#define EPB 2048      // edges per bucket_kernel block
#define NBLK_BUCKET ((N_EDGES + EPB - 1) / EPB)
#define NCVT4 (N_NODES * 128 / 4)   // 1,600,000 float4 groups for feat cvt

// ---------------- workspace layout ----------------
// int region (int offsets; bytes = x4):
//   rowptr  [50001]   @ 100000   (bytes 400000..600004)
//   eidx    [800000]u16 @ int 150016 (bytes 600064..2200064)
//   bcnt    [196]     @ 950528   (bytes 3802112..3802896)
// bf16 region (ushort offsets; bytes = x2):
//   wT    [49152]     @ 1920000  (bytes 3840000..3938304)
//   featb [50000*128] @ 2000000  (bytes 4000000..16800000)
//   agg1b [50000*128] @ 8400000  (bytes 16800000..29600000)
//   h1b   [50000*128] @ 14800000 (bytes 29600000..42400000; bucket u32[196*6144]=4.8MB aliased pre-gemm1)
//   p2b   [50000*64]  @ 21200000 (bytes 42400000..48800000)
#define IOFF_ROWPTR  100000
#define IOFF_EIDX    150016
#define IOFF_BCNT    950528
#define UOFF_WT      1920000
#define UOFF_FEATB   2000000
#define UOFF_AGG1B   8400000
#define UOFF_H1B     14800000
#define UOFF_P2B     21200000

__device__ __forceinline__ float bf2f(uint_t u) {
    return __uint_as_float(u << 16);
}
__device__ __forceinline__ uint_t f2bf(float f) {
    uint_t x = __float_as_uint(f);
    return (x + 0x7FFFu + ((x >> 16) & 1u)) >> 16;  // RNE
}

// fused prep: feat f32->bf16 + weight transpose/convert + bcnt zeroing
__global__ __launch_bounds__(256) void prep_kernel(const float* __restrict__ feat,
                                                   const float* __restrict__ Ws1,
                                                   const float* __restrict__ Wn1,
                                                   const float* __restrict__ Ws2,
                                                   const float* __restrict__ Wn2,
                                                   ushort_t* __restrict__ featb,
                                                   ushort_t* __restrict__ wT,
                                                   int* __restrict__ bcnt) {
    int i = blockIdx.x * 256 + threadIdx.x;
    if (i < NCVT4) {
        float4 v = ((const float4*)feat)[i];
        uint2 o;
        o.x = f2bf(v.x) | (f2bf(v.y) << 16);
        o.y = f2bf(v.z) | (f2bf(v.w) << 16);
        ((uint2*)featb)[i] = o;
        return;
    }
    int j = i - NCVT4;
    if (j < 49152) {
        float v;
        if (j < 16384) {
            int n = j >> 7, k = j & 127;
            v = Ws1[k * 128 + n];
        } else if (j < 32768) {
            int jj = j - 16384, n = jj >> 7, k = jj & 127;
            v = Wn1[k * 128 + n];
        } else if (j < 40960) {
            int jj = j - 32768, n = jj >> 7, k = jj & 127;
            v = Wn2[k * 64 + n];
        } else {
            int jj = j - 40960, n = jj >> 7, k = jj & 127;
            v = Ws2[k * 64 + n];
        }
        wT[j] = (ushort_t)f2bf(v);
        return;
    }
    int z = j - 49152;
    if (z < NB) bcnt[z] = 0;
}

// ---- bucketed CSR build ----
// phase 1: partition edges into 196 buckets (LDS-staged, coalesced flush).
// 391 blocks x 2048 edges; LDS ~27KB -> ~5 blocks/CU; halves hot-counter atomics vs EPB=1024.
__global__ __launch_bounds__(256) void bucket_kernel(const int* __restrict__ src,
                                                     const int* __restrict__ dst,
                                                     uint_t* __restrict__ bucket,
                                                     int* __restrict__ bcnt) {
    __shared__ uint_t stage[NB][SDEPTH];
    __shared__ int lcnt[NB];
    __shared__ int gbase[NB];
    int tid = threadIdx.x;
    for (int i = tid; i < NB; i += 256) lcnt[i] = 0;
    __syncthreads();
    int e0 = blockIdx.x * EPB;
#pragma unroll
    for (int it = 0; it < EPB / 256; ++it) {
        int e = e0 + it * 256 + tid;
        if (e < N_EDGES) {
            int d = dst[e], s = src[e];
            uint_t v = ((uint_t)d << 16) | (uint_t)s;
            int b = d >> 8;
            int slot = atomicAdd(&lcnt[b], 1);
            if (slot < SDEPTH) {
                stage[b][slot] = v;
            } else {  // rare overflow: direct reservation
                int p = atomicAdd(&bcnt[b], 1);
                bucket[(long)b * BCAP + p] = v;
            }
        }
    }
    __syncthreads();
    if (tid < NB) {
        int n = min(lcnt[tid], SDEPTH);
        gbase[tid] = (n > 0) ? atomicAdd(&bcnt[tid], n) : 0;
    }
    __syncthreads();
    for (int s = tid; s < NB * SDEPTH; s += 256) {
        int b = s >> 5, i = s & (SDEPTH - 1);
        if (i < min(lcnt[b], SDEPTH))
            bucket[(long)b * BCAP + gbase[b] + i] = stage[b][i];
    }
}

// phase 2: per-bucket local CSR. Each block self-computes its bucket base by
// scanning the 196-entry bcnt in LDS (scan196 launch deleted).
// eidx (u16) writes confined to one contiguous ~8KB range per block.
__global__ __launch_bounds__(1024) void fill_bucket(const uint_t* __restrict__ bucket,
                                                    const int* __restrict__ bcnt,
                                                    int* __restrict__ rowptr,
                                                    ushort_t* __restrict__ eidx) {
    __shared__ int pref[256];
    __shared__ int hist[256];
    __shared__ int excl[256];
    __shared__ int fp[256];
    int b = blockIdx.x, tid = threadIdx.x;
    if (tid < 256) {
        pref[tid] = (tid < NB) ? bcnt[tid] : 0;
        hist[tid] = 0;
        fp[tid] = 0;
    }
    __syncthreads();
    // inclusive scan of bucket counts (256 entries, first 256 threads)
    for (int off = 1; off < 256; off <<= 1) {
        int t = 0;
        if (tid < 256 && tid >= off) t = pref[tid - off];
        __syncthreads();
        if (tid < 256) pref[tid] += t;
        __syncthreads();
    }
    int n = bcnt[b];
    int base = pref[b] - n;  // exclusive base for this bucket
    if (b == NB - 1 && tid == 0) rowptr[N_NODES] = pref[NB - 1];
    int nodebase = b << 8;
    const uint_t* bk = bucket + (long)b * BCAP;
    for (int i = tid; i < n; i += 1024) {
        int d = (int)(bk[i] >> 16) - nodebase;
        atomicAdd(&hist[d], 1);
    }
    __syncthreads();
    int v = 0;
    if (tid < 256) { v = hist[tid]; excl[tid] = v; }
    __syncthreads();
    for (int off = 1; off < 256; off <<= 1) {
        int t = 0;
        if (tid < 256 && tid >= off) t = excl[tid - off];
        __syncthreads();
        if (tid < 256) excl[tid] += t;
        __syncthreads();
    }
    if (tid < 256) {
        excl[tid] -= v;
        int node = nodebase + tid;
        if (node < N_NODES) rowptr[node] = base + excl[tid];
    }
    __syncthreads();
    for (int i = tid; i < n; i += 1024) {
        uint_t vv = bk[i];
        int d = (int)(vv >> 16) - nodebase;
        int off = atomicAdd(&fp[d], 1);
        eidx[base + excl[d] + off] = (ushort_t)(vv & 0xFFFFu);
    }
}

// one wave per node; 16 lanes cover one 256B row (16B/lane), 4 edges per wave-load.
__global__ __launch_bounds__(256) void gather128_kernel(const int* __restrict__ rowptr,
                                                        const ushort_t* __restrict__ eidx,
                                                        const ushort_t* __restrict__ xb,
                                                        ushort_t* __restrict__ aggb) {
    int node = blockIdx.x * 4 + (threadIdx.x >> 6);
    int lane = threadIdx.x & 63;
    if (node >= N_NODES) return;
    int q = lane >> 4;    // edge slot 0..3
    int sl = lane & 15;   // col group: cols sl*8 .. sl*8+7
    int beg = rowptr[node], end = rowptr[node + 1];
    float acc[8];
#pragma unroll
    for (int j = 0; j < 8; ++j) acc[j] = 0.f;

    int e = beg;
    for (; e + 7 < end; e += 8) {
        int sA = eidx[e + q];
        int sB = eidx[e + 4 + q];
        uint4 vA = *(const uint4*)(xb + (long)sA * 128 + sl * 8);
        uint4 vB = *(const uint4*)(xb + (long)sB * 128 + sl * 8);
        acc[0] += bf2f(vA.x & 0xffffu); acc[1] += bf2f(vA.x >> 16);
        acc[2] += bf2f(vA.y & 0xffffu); acc[3] += bf2f(vA.y >> 16);
        acc[4] += bf2f(vA.z & 0xffffu); acc[5] += bf2f(vA.z >> 16);
        acc[6] += bf2f(vA.w & 0xffffu); acc[7] += bf2f(vA.w >> 16);
        acc[0] += bf2f(vB.x & 0xffffu); acc[1] += bf2f(vB.x >> 16);
        acc[2] += bf2f(vB.y & 0xffffu); acc[3] += bf2f(vB.y >> 16);
        acc[4] += bf2f(vB.z & 0xffffu); acc[5] += bf2f(vB.z >> 16);
        acc[6] += bf2f(vB.w & 0xffffu); acc[7] += bf2f(vB.w >> 16);
    }
    for (; e + 3 < end; e += 4) {
        int s = eidx[e + q];
        uint4 v = *(const uint4*)(xb + (long)s * 128 + sl * 8);
        acc[0] += bf2f(v.x & 0xffffu); acc[1] += bf2f(v.x >> 16);
        acc[2] += bf2f(v.y & 0xffffu); acc[3] += bf2f(v.y >> 16);
        acc[4] += bf2f(v.z & 0xffffu); acc[5] += bf2f(v.z >> 16);
        acc[6] += bf2f(v.w & 0xffffu); acc[7] += bf2f(v.w >> 16);
    }
    if (e + q < end) {  // tail: 1..3 edges, slots q < remainder
        int s = eidx[e + q];
        uint4 v = *(const uint4*)(xb + (long)s * 128 + sl * 8);
        acc[0] += bf2f(v.x & 0xffffu); acc[1] += bf2f(v.x >> 16);
        acc[2] += bf2f(v.y & 0xffffu); acc[3] += bf2f(v.y >> 16);
        acc[4] += bf2f(v.z & 0xffffu); acc[5] += bf2f(v.z >> 16);
        acc[6] += bf2f(v.w & 0xffffu); acc[7] += bf2f(v.w >> 16);
    }
#pragma unroll
    for (int j = 0; j < 8; ++j) {
        acc[j] += __shfl_xor(acc[j], 16);
        acc[j] += __shfl_xor(acc[j], 32);
    }
    float inv = (end > beg) ? 1.0f / (float)(end - beg) : 0.f;
    if (lane < 16) {
        uint4 o;
        o.x = f2bf(acc[0] * inv) | (f2bf(acc[1] * inv) << 16);
        o.y = f2bf(acc[2] * inv) | (f2bf(acc[3] * inv) << 16);
        o.z = f2bf(acc[4] * inv) | (f2bf(acc[5] * inv) << 16);
        o.w = f2bf(acc[6] * inv) | (f2bf(acc[7] * inv) << 16);
        *(uint4*)(aggb + (long)node * 128 + sl * 8) = o;
    }
}

// one wave per node; 16 lanes cover one 128B row (8B/lane), 4 edges per wave-load.
__global__ __launch_bounds__(256) void gather64_add_kernel(const int* __restrict__ rowptr,
                                                           const ushort_t* __restrict__ eidx,
                                                           const ushort_t* __restrict__ p2b,
                                                           float* __restrict__ out) {
    int node = blockIdx.x * 4 + (threadIdx.x >> 6);
    int lane = threadIdx.x & 63;
    if (node >= N_NODES) return;
    int q = lane >> 4;    // edge slot 0..3
    int sl = lane & 15;   // col group: cols sl*4 .. sl*4+3
    int beg = rowptr[node], end = rowptr[node + 1];
    float acc[4];
#pragma unroll
    for (int j = 0; j < 4; ++j) acc[j] = 0.f;

    int e = beg;
    for (; e + 7 < end; e += 8) {
        int sA = eidx[e + q];
        int sB = eidx[e + 4 + q];
        uint2 vA = *(const uint2*)(p2b + (long)sA * 64 + sl * 4);
        uint2 vB = *(const uint2*)(p2b + (long)sB * 64 + sl * 4);
        acc[0] += bf2f(vA.x & 0xffffu); acc[1] += bf2f(vA.x >> 16);
        acc[2] += bf2f(vA.y & 0xffffu); acc[3] += bf2f(vA.y >> 16);
        acc[0] += bf2f(vB.x & 0xffffu); acc[1] += bf2f(vB.x >> 16);
        acc[2] += bf2f(vB.y & 0xffffu); acc[3] += bf2f(vB.y >> 16);
    }
    for (; e + 3 < end; e += 4) {
        int s = eidx[e + q];
        uint2 v = *(const uint2*)(p2b + (long)s * 64 + sl * 4);
        acc[0] += bf2f(v.x & 0xffffu); acc[1] += bf2f(v.x >> 16);
        acc[2] += bf2f(v.y & 0xffffu); acc[3] += bf2f(v.y >> 16);
    }
    if (e + q < end) {
        int s = eidx[e + q];
        uint2 v = *(const uint2*)(p2b + (long)s * 64 + sl * 4);
        acc[0] += bf2f(v.x & 0xffffu); acc[1] += bf2f(v.x >> 16);
        acc[2] += bf2f(v.y & 0xffffu); acc[3] += bf2f(v.y >> 16);
    }
#pragma unroll
    for (int j = 0; j < 4; ++j) {
        acc[j] += __shfl_xor(acc[j], 16);
        acc[j] += __shfl_xor(acc[j], 32);
    }
    float inv = (end > beg) ? 1.0f / (float)(end - beg) : 0.f;
    if (lane < 16) {
        float4* po = (float4*)(out + (long)node * 64 + sl * 4);
        float4 o = *po;
        o.x += acc[0] * inv;
        o.y += acc[1] * inv;
        o.z += acc[2] * inv;
        o.w += acc[3] * inv;
        *po = o;
    }
}

// ---------------- MFMA GEMMs (no LDS; frags straight from global) ----------------
// A frag (16x16x32 bf16): row = lane&15, k = (lane>>4)*8 + e  -> 16B contiguous
// B frag: col = lane&15, same k                               -> 16B contiguous in W^T
// D frag: col = lane&15, row = (lane>>4)*4 + reg

__global__ __launch_bounds__(256) void gemm1_mfma(const ushort_t* __restrict__ featb,
                                                  const ushort_t* __restrict__ agg1b,
                                                  const ushort_t* __restrict__ wT,
                                                  const float* __restrict__ b,
                                                  ushort_t* __restrict__ h1b) {
    int lane = threadIdx.x & 63;
    int w = threadIdx.x >> 6;
    int mbase = blockIdx.x * 128 + w * 32;
    int lr = lane & 15;
    int kg = (lane >> 4) * 8;

    long r0 = mbase + lr;
    long r1 = mbase + 16 + lr;
    if (r0 > N_NODES - 1) r0 = N_NODES - 1;
    if (r1 > N_NODES - 1) r1 = N_NODES - 1;

    f32x4 acc[2][8];
#pragma unroll
    for (int mt = 0; mt < 2; ++mt)
#pragma unroll
        for (int nt = 0; nt < 8; ++nt) acc[mt][nt] = (f32x4){0.f, 0.f, 0.f, 0.f};

#pragma unroll
    for (int pass = 0; pass < 2; ++pass) {
        const ushort_t* a = pass ? agg1b : featb;
        const ushort_t* wt = wT + pass * (128 * 128);
#pragma unroll
        for (int ks = 0; ks < 4; ++ks) {
            int k = ks * 32 + kg;
            bf16x8 a0 = *(const bf16x8*)(a + r0 * 128 + k);
            bf16x8 a1 = *(const bf16x8*)(a + r1 * 128 + k);
#pragma unroll
            for (int nt = 0; nt < 8; ++nt) {
                bf16x8 bb = *(const bf16x8*)(wt + (nt * 16 + lr) * 128 + k);
                acc[0][nt] = __builtin_amdgcn_mfma_f32_16x16x32_bf16(a0, bb, acc[0][nt], 0, 0, 0);
                acc[1][nt] = __builtin_amdgcn_mfma_f32_16x16x32_bf16(a1, bb, acc[1][nt], 0, 0, 0);
            }
        }
    }

    int drow = (lane >> 4) * 4;
#pragma unroll
    for (int nt = 0; nt < 8; ++nt) {
        int n = nt * 16 + lr;
        float bias = b[n];
#pragma unroll
        for (int mt = 0; mt < 2; ++mt) {
#pragma unroll
            for (int r = 0; r < 4; ++r) {
                int row = mbase + mt * 16 + drow + r;
                if (row < N_NODES) {
                    float v = fmaxf(acc[mt][nt][r] + bias, 0.f);
                    h1b[(long)row * 128 + n] = (ushort_t)f2bf(v);
                }
            }
        }
    }
}

// fused layer-2: p2b = bf16(h1b@Wn2); out = h1b@Ws2 + b2  (A-frags shared)
__global__ __launch_bounds__(256) void gemm2_mfma(const ushort_t* __restrict__ h1b,
                                                  const ushort_t* __restrict__ wT2,  // [WnT2 | WsT2]
                                                  const float* __restrict__ b2,
                                                  ushort_t* __restrict__ p2b,
                                                  float* __restrict__ out) {
    int lane = threadIdx.x & 63;
    int w = threadIdx.x >> 6;
    int mbase = blockIdx.x * 128 + w * 32;
    int lr = lane & 15;
    int kg = (lane >> 4) * 8;

    long r0 = mbase + lr;
    long r1 = mbase + 16 + lr;
    if (r0 > N_NODES - 1) r0 = N_NODES - 1;
    if (r1 > N_NODES - 1) r1 = N_NODES - 1;

    f32x4 accP[2][4], accO[2][4];
#pragma unroll
    for (int mt = 0; mt < 2; ++mt)
#pragma unroll
        for (int nt = 0; nt < 4; ++nt) {
            accP[mt][nt] = (f32x4){0.f, 0.f, 0.f, 0.f};
            accO[mt][nt] = (f32x4){0.f, 0.f, 0.f, 0.f};
        }

#pragma unroll
    for (int ks = 0; ks < 4; ++ks) {
        int k = ks * 32 + kg;
        bf16x8 a0 = *(const bf16x8*)(h1b + r0 * 128 + k);
        bf16x8 a1 = *(const bf16x8*)(h1b + r1 * 128 + k);
#pragma unroll
        for (int nt = 0; nt < 4; ++nt) {
            bf16x8 bn = *(const bf16x8*)(wT2 + (nt * 16 + lr) * 128 + k);
            bf16x8 bs = *(const bf16x8*)(wT2 + 8192 + (nt * 16 + lr) * 128 + k);
            accP[0][nt] = __builtin_amdgcn_mfma_f32_16x16x32_bf16(a0, bn, accP[0][nt], 0, 0, 0);
            accP[1][nt] = __builtin_amdgcn_mfma_f32_16x16x32_bf16(a1, bn, accP[1][nt], 0, 0, 0);
            accO[0][nt] = __builtin_amdgcn_mfma_f32_16x16x32_bf16(a0, bs, accO[0][nt], 0, 0, 0);
            accO[1][nt] = __builtin_amdgcn_mfma_f32_16x16x32_bf16(a1, bs, accO[1][nt], 0, 0, 0);
        }
    }

    int drow = (lane >> 4) * 4;
#pragma unroll
    for (int nt = 0; nt < 4; ++nt) {
        int n = nt * 16 + lr;
        float bias = b2[n];
#pragma unroll
        for (int mt = 0; mt < 2; ++mt) {
#pragma unroll
            for (int r = 0; r < 4; ++r) {
                int row = mbase + mt * 16 + drow + r;
                if (row < N_NODES) {
                    p2b[(long)row * 64 + n] = (ushort_t)f2bf(accP[mt][nt][r]);
                    out[(long)row * 64 + n] = accO[mt][nt][r] + bias;
                }
            }
        }
    }
}

extern "C" void kernel_launch(void* const* d_in, const int* in_sizes, int n_in,
                              void* d_out, int out_size, void* d_ws, size_t ws_size,
                              hipStream_t stream) {
    const float* feat = (const float*)d_in[0];
    const int* src    = (const int*)d_in[1];
    const int* dst    = (const int*)d_in[2];
    const float* Ws1  = (const float*)d_in[3];
    const float* Wn1  = (const float*)d_in[4];
    const float* b1   = (const float*)d_in[5];
    const float* Ws2  = (const float*)d_in[6];
    const float* Wn2  = (const float*)d_in[7];
    const float* b2   = (const float*)d_in[8];
    float* out = (float*)d_out;

    int* wsi      = (int*)d_ws;
    ushort_t* wsu = (ushort_t*)d_ws;
    int* rowptr       = wsi + IOFF_ROWPTR;
    ushort_t* eidx    = (ushort_t*)(wsi + IOFF_EIDX);
    int* bcnt         = wsi + IOFF_BCNT;
    ushort_t* wT    = wsu + UOFF_WT;
    ushort_t* featb = wsu + UOFF_FEATB;
    ushort_t* agg1b = wsu + UOFF_AGG1B;
    ushort_t* h1b   = wsu + UOFF_H1B;
    ushort_t* p2b   = wsu + UOFF_P2B;
    uint_t* bucket  = (uint_t*)(wsu + UOFF_H1B);  // aliased: dead before gemm1 writes h1b

    // fused prep: feat -> bf16 + weight transpose/convert + bcnt zeroing
    prep_kernel<<<(NCVT4 + 49152 + NB + 255) / 256, 256, 0, stream>>>(
        feat, Ws1, Wn1, Ws2, Wn2, featb, wT, bcnt);

    // ---- bucketed CSR build ----
    bucket_kernel<<<NBLK_BUCKET, 256, 0, stream>>>(src, dst, bucket, bcnt);
    fill_bucket<<<NB, 1024, 0, stream>>>(bucket, bcnt, rowptr, eidx);

    // ---- layer 1 ----
    gather128_kernel<<<(N_NODES + 3) / 4, 256, 0, stream>>>(rowptr, eidx, featb, agg1b);
    gemm1_mfma<<<(N_NODES + 127) / 128, 256, 0, stream>>>(featb, agg1b, wT, b1, h1b);

    // ---- layer 2 (fused dual GEMM, aggregate-after-matmul) ----
    gemm2_mfma<<<(N_NODES + 127) / 128, 256, 0, stream>>>(h1b, wT + 32768, b2, p2b, out);
    gather64_add_kernel<<<(N_NODES + 3) / 4, 256, 0, stream>>>(rowptr, eidx, p2b, out);
}

// Round 12
// 198.678 us; speedup vs baseline: 1.9492x; 1.0746x over previous
//
#include <hip/hip_runtime.h>

#define N_NODES 50000
#define N_EDGES 800000
// IN=128, HID=128, OUT=64

typedef unsigned short ushort_t;
typedef unsigned int uint_t;
typedef __attribute__((ext_vector_type(8))) short bf16x8;
typedef __attribute__((ext_vector_type(4))) float f32x4;

#define NB 196        // buckets: dst>>8 (256 nodes per bucket)
#define BCAP 6144     // per-bucket capacity (avg 4082, +safety)
#define SDEPTH 32     // LDS staging depth per bucket
#define EPB 2048      // edges per bucket_kernel block
#define NBLK_BUCKET ((N_EDGES + EPB - 1) / EPB)
#define NCVT4 (N_NODES * 128 / 4)   // 1,600,000 float4 groups for feat cvt

// ---------------- workspace layout ----------------
// int region (int offsets; bytes = x4):
//   rowptr  [50001]   @ 100000   (bytes 400000..600004)
//   eidx    [800000]u16 @ int 150016 (bytes 600064..2200064)
//   bcnt    [196]     @ 950528   (bytes 3802112..3802896)
// bf16 region (ushort offsets; bytes = x2):
//   wT    [49152]     @ 1920000  (bytes 3840000..3938304)
//   featb [50000*128] @ 2000000  (bytes 4000000..16800000)
//   agg1b [50000*128] @ 8400000  (bytes 16800000..29600000)
//   bucket u32[196*6144] @ ushort 14800000 (4.8MB; dead after fill_bucket)
//   p2b   [50000*64]  @ 21200000 (bytes 42400000..48800000)
#define IOFF_ROWPTR  100000
#define IOFF_EIDX    150016
#define IOFF_BCNT    950528
#define UOFF_WT      1920000
#define UOFF_FEATB   2000000
#define UOFF_AGG1B   8400000
#define UOFF_BUCKET  14800000
#define UOFF_P2B     21200000

__device__ __forceinline__ float bf2f(uint_t u) {
    return __uint_as_float(u << 16);
}
__device__ __forceinline__ uint_t f2bf(float f) {
    uint_t x = __float_as_uint(f);
    return (x + 0x7FFFu + ((x >> 16) & 1u)) >> 16;  // RNE
}

// fused prep: feat f32->bf16 + weight transpose/convert + bcnt zeroing
__global__ __launch_bounds__(256) void prep_kernel(const float* __restrict__ feat,
                                                   const float* __restrict__ Ws1,
                                                   const float* __restrict__ Wn1,
                                                   const float* __restrict__ Ws2,
                                                   const float* __restrict__ Wn2,
                                                   ushort_t* __restrict__ featb,
                                                   ushort_t* __restrict__ wT,
                                                   int* __restrict__ bcnt) {
    int i = blockIdx.x * 256 + threadIdx.x;
    if (i < NCVT4) {
        float4 v = ((const float4*)feat)[i];
        uint2 o;
        o.x = f2bf(v.x) | (f2bf(v.y) << 16);
        o.y = f2bf(v.z) | (f2bf(v.w) << 16);
        ((uint2*)featb)[i] = o;
        return;
    }
    int j = i - NCVT4;
    if (j < 49152) {
        float v;
        if (j < 16384) {
            int n = j >> 7, k = j & 127;
            v = Ws1[k * 128 + n];
        } else if (j < 32768) {
            int jj = j - 16384, n = jj >> 7, k = jj & 127;
            v = Wn1[k * 128 + n];
        } else if (j < 40960) {
            int jj = j - 32768, n = jj >> 7, k = jj & 127;
            v = Wn2[k * 64 + n];
        } else {
            int jj = j - 40960, n = jj >> 7, k = jj & 127;
            v = Ws2[k * 64 + n];
        }
        wT[j] = (ushort_t)f2bf(v);
        return;
    }
    int z = j - 49152;
    if (z < NB) bcnt[z] = 0;
}

// ---- bucketed CSR build ----
__global__ __launch_bounds__(256) void bucket_kernel(const int* __restrict__ src,
                                                     const int* __restrict__ dst,
                                                     uint_t* __restrict__ bucket,
                                                     int* __restrict__ bcnt) {
    __shared__ uint_t stage[NB][SDEPTH];
    __shared__ int lcnt[NB];
    __shared__ int gbase[NB];
    int tid = threadIdx.x;
    for (int i = tid; i < NB; i += 256) lcnt[i] = 0;
    __syncthreads();
    int e0 = blockIdx.x * EPB;
#pragma unroll
    for (int it = 0; it < EPB / 256; ++it) {
        int e = e0 + it * 256 + tid;
        if (e < N_EDGES) {
            int d = dst[e], s = src[e];
            uint_t v = ((uint_t)d << 16) | (uint_t)s;
            int b = d >> 8;
            int slot = atomicAdd(&lcnt[b], 1);
            if (slot < SDEPTH) {
                stage[b][slot] = v;
            } else {  // rare overflow: direct reservation
                int p = atomicAdd(&bcnt[b], 1);
                bucket[(long)b * BCAP + p] = v;
            }
        }
    }
    __syncthreads();
    if (tid < NB) {
        int n = min(lcnt[tid], SDEPTH);
        gbase[tid] = (n > 0) ? atomicAdd(&bcnt[tid], n) : 0;
    }
    __syncthreads();
    for (int s = tid; s < NB * SDEPTH; s += 256) {
        int b = s >> 5, i = s & (SDEPTH - 1);
        if (i < min(lcnt[b], SDEPTH))
            bucket[(long)b * BCAP + gbase[b] + i] = stage[b][i];
    }
}

// per-bucket local CSR; block self-computes its bucket base from bcnt scan
__global__ __launch_bounds__(1024) void fill_bucket(const uint_t* __restrict__ bucket,
                                                    const int* __restrict__ bcnt,
                                                    int* __restrict__ rowptr,
                                                    ushort_t* __restrict__ eidx) {
    __shared__ int pref[256];
    __shared__ int hist[256];
    __shared__ int excl[256];
    __shared__ int fp[256];
    int b = blockIdx.x, tid = threadIdx.x;
    if (tid < 256) {
        pref[tid] = (tid < NB) ? bcnt[tid] : 0;
        hist[tid] = 0;
        fp[tid] = 0;
    }
    __syncthreads();
    for (int off = 1; off < 256; off <<= 1) {
        int t = 0;
        if (tid < 256 && tid >= off) t = pref[tid - off];
        __syncthreads();
        if (tid < 256) pref[tid] += t;
        __syncthreads();
    }
    int n = bcnt[b];
    int base = pref[b] - n;  // exclusive base for this bucket
    if (b == NB - 1 && tid == 0) rowptr[N_NODES] = pref[NB - 1];
    int nodebase = b << 8;
    const uint_t* bk = bucket + (long)b * BCAP;
    for (int i = tid; i < n; i += 1024) {
        int d = (int)(bk[i] >> 16) - nodebase;
        atomicAdd(&hist[d], 1);
    }
    __syncthreads();
    int v = 0;
    if (tid < 256) { v = hist[tid]; excl[tid] = v; }
    __syncthreads();
    for (int off = 1; off < 256; off <<= 1) {
        int t = 0;
        if (tid < 256 && tid >= off) t = excl[tid - off];
        __syncthreads();
        if (tid < 256) excl[tid] += t;
        __syncthreads();
    }
    if (tid < 256) {
        excl[tid] -= v;
        int node = nodebase + tid;
        if (node < N_NODES) rowptr[node] = base + excl[tid];
    }
    __syncthreads();
    for (int i = tid; i < n; i += 1024) {
        uint_t vv = bk[i];
        int d = (int)(vv >> 16) - nodebase;
        int off = atomicAdd(&fp[d], 1);
        eidx[base + excl[d] + off] = (ushort_t)(vv & 0xFFFFu);
    }
}

// one wave per node; 16 lanes cover one 256B row (16B/lane), 4 edges per wave-load.
__global__ __launch_bounds__(256) void gather128_kernel(const int* __restrict__ rowptr,
                                                        const ushort_t* __restrict__ eidx,
                                                        const ushort_t* __restrict__ xb,
                                                        ushort_t* __restrict__ aggb) {
    int node = blockIdx.x * 4 + (threadIdx.x >> 6);
    int lane = threadIdx.x & 63;
    if (node >= N_NODES) return;
    int q = lane >> 4;    // edge slot 0..3
    int sl = lane & 15;   // col group: cols sl*8 .. sl*8+7
    int beg = rowptr[node], end = rowptr[node + 1];
    float acc[8];
#pragma unroll
    for (int j = 0; j < 8; ++j) acc[j] = 0.f;

    int e = beg;
    for (; e + 7 < end; e += 8) {
        int sA = eidx[e + q];
        int sB = eidx[e + 4 + q];
        uint4 vA = *(const uint4*)(xb + (long)sA * 128 + sl * 8);
        uint4 vB = *(const uint4*)(xb + (long)sB * 128 + sl * 8);
        acc[0] += bf2f(vA.x & 0xffffu); acc[1] += bf2f(vA.x >> 16);
        acc[2] += bf2f(vA.y & 0xffffu); acc[3] += bf2f(vA.y >> 16);
        acc[4] += bf2f(vA.z & 0xffffu); acc[5] += bf2f(vA.z >> 16);
        acc[6] += bf2f(vA.w & 0xffffu); acc[7] += bf2f(vA.w >> 16);
        acc[0] += bf2f(vB.x & 0xffffu); acc[1] += bf2f(vB.x >> 16);
        acc[2] += bf2f(vB.y & 0xffffu); acc[3] += bf2f(vB.y >> 16);
        acc[4] += bf2f(vB.z & 0xffffu); acc[5] += bf2f(vB.z >> 16);
        acc[6] += bf2f(vB.w & 0xffffu); acc[7] += bf2f(vB.w >> 16);
    }
    for (; e + 3 < end; e += 4) {
        int s = eidx[e + q];
        uint4 v = *(const uint4*)(xb + (long)s * 128 + sl * 8);
        acc[0] += bf2f(v.x & 0xffffu); acc[1] += bf2f(v.x >> 16);
        acc[2] += bf2f(v.y & 0xffffu); acc[3] += bf2f(v.y >> 16);
        acc[4] += bf2f(v.z & 0xffffu); acc[5] += bf2f(v.z >> 16);
        acc[6] += bf2f(v.w & 0xffffu); acc[7] += bf2f(v.w >> 16);
    }
    if (e + q < end) {  // tail: 1..3 edges, slots q < remainder
        int s = eidx[e + q];
        uint4 v = *(const uint4*)(xb + (long)s * 128 + sl * 8);
        acc[0] += bf2f(v.x & 0xffffu); acc[1] += bf2f(v.x >> 16);
        acc[2] += bf2f(v.y & 0xffffu); acc[3] += bf2f(v.y >> 16);
        acc[4] += bf2f(v.z & 0xffffu); acc[5] += bf2f(v.z >> 16);
        acc[6] += bf2f(v.w & 0xffffu); acc[7] += bf2f(v.w >> 16);
    }
#pragma unroll
    for (int j = 0; j < 8; ++j) {
        acc[j] += __shfl_xor(acc[j], 16);
        acc[j] += __shfl_xor(acc[j], 32);
    }
    float inv = (end > beg) ? 1.0f / (float)(end - beg) : 0.f;
    if (lane < 16) {
        uint4 o;
        o.x = f2bf(acc[0] * inv) | (f2bf(acc[1] * inv) << 16);
        o.y = f2bf(acc[2] * inv) | (f2bf(acc[3] * inv) << 16);
        o.z = f2bf(acc[4] * inv) | (f2bf(acc[5] * inv) << 16);
        o.w = f2bf(acc[6] * inv) | (f2bf(acc[7] * inv) << 16);
        *(uint4*)(aggb + (long)node * 128 + sl * 8) = o;
    }
}

// one wave per node; 16 lanes cover one 128B row (8B/lane), 4 edges per wave-load.
__global__ __launch_bounds__(256) void gather64_add_kernel(const int* __restrict__ rowptr,
                                                           const ushort_t* __restrict__ eidx,
                                                           const ushort_t* __restrict__ p2b,
                                                           float* __restrict__ out) {
    int node = blockIdx.x * 4 + (threadIdx.x >> 6);
    int lane = threadIdx.x & 63;
    if (node >= N_NODES) return;
    int q = lane >> 4;    // edge slot 0..3
    int sl = lane & 15;   // col group: cols sl*4 .. sl*4+3
    int beg = rowptr[node], end = rowptr[node + 1];
    float acc[4];
#pragma unroll
    for (int j = 0; j < 4; ++j) acc[j] = 0.f;

    int e = beg;
    for (; e + 7 < end; e += 8) {
        int sA = eidx[e + q];
        int sB = eidx[e + 4 + q];
        uint2 vA = *(const uint2*)(p2b + (long)sA * 64 + sl * 4);
        uint2 vB = *(const uint2*)(p2b + (long)sB * 64 + sl * 4);
        acc[0] += bf2f(vA.x & 0xffffu); acc[1] += bf2f(vA.x >> 16);
        acc[2] += bf2f(vA.y & 0xffffu); acc[3] += bf2f(vA.y >> 16);
        acc[0] += bf2f(vB.x & 0xffffu); acc[1] += bf2f(vB.x >> 16);
        acc[2] += bf2f(vB.y & 0xffffu); acc[3] += bf2f(vB.y >> 16);
    }
    for (; e + 3 < end; e += 4) {
        int s = eidx[e + q];
        uint2 v = *(const uint2*)(p2b + (long)s * 64 + sl * 4);
        acc[0] += bf2f(v.x & 0xffffu); acc[1] += bf2f(v.x >> 16);
        acc[2] += bf2f(v.y & 0xffffu); acc[3] += bf2f(v.y >> 16);
    }
    if (e + q < end) {
        int s = eidx[e + q];
        uint2 v = *(const uint2*)(p2b + (long)s * 64 + sl * 4);
        acc[0] += bf2f(v.x & 0xffffu); acc[1] += bf2f(v.x >> 16);
        acc[2] += bf2f(v.y & 0xffffu); acc[3] += bf2f(v.y >> 16);
    }
#pragma unroll
    for (int j = 0; j < 4; ++j) {
        acc[j] += __shfl_xor(acc[j], 16);
        acc[j] += __shfl_xor(acc[j], 32);
    }
    float inv = (end > beg) ? 1.0f / (float)(end - beg) : 0.f;
    if (lane < 16) {
        float4* po = (float4*)(out + (long)node * 64 + sl * 4);
        float4 o = *po;
        o.x += acc[0] * inv;
        o.y += acc[1] * inv;
        o.z += acc[2] * inv;
        o.w += acc[3] * inv;
        *po = o;
    }
}

// ---------------- fused MFMA layers (h1 lives in LDS, never in HBM) ----------------
// A frag (16x16x32 bf16): row = lane&15, k = (lane>>4)*8 + e  -> 16B contiguous
// B frag: col = lane&15, same k                               -> 16B contiguous in W^T
// D frag: col = lane&15, row = (lane>>4)*4 + reg
// h1 LDS tile [128][128] bf16, XOR-swizzled: col' = col ^ ((row&7)<<3)
// (swizzle keeps 8-ushort groups intact since k-slices are 8-aligned; phase-2
//  ds_read_b128 across 16 rows spreads over 8 swizzle classes -> 2-way = free)
__global__ __launch_bounds__(256) void gemm12_mfma(const ushort_t* __restrict__ featb,
                                                   const ushort_t* __restrict__ agg1b,
                                                   const ushort_t* __restrict__ wT,
                                                   const float* __restrict__ b1,
                                                   const float* __restrict__ b2,
                                                   ushort_t* __restrict__ p2b,
                                                   float* __restrict__ out) {
    __shared__ ushort_t hlds[128][128];  // 32 KB
    int lane = threadIdx.x & 63;
    int w = threadIdx.x >> 6;
    int mbase = blockIdx.x * 128 + w * 32;
    int lbase = w * 32;          // block-local row base for this wave
    int lr = lane & 15;
    int kg = (lane >> 4) * 8;
    int drow = (lane >> 4) * 4;

    // ---- phase 1: h1 = relu(feat@Ws1 + agg1@Wn1 + b1) ----
    long r0 = mbase + lr;
    long r1 = mbase + 16 + lr;
    if (r0 > N_NODES - 1) r0 = N_NODES - 1;
    if (r1 > N_NODES - 1) r1 = N_NODES - 1;

    f32x4 acc[2][8];
#pragma unroll
    for (int mt = 0; mt < 2; ++mt)
#pragma unroll
        for (int nt = 0; nt < 8; ++nt) acc[mt][nt] = (f32x4){0.f, 0.f, 0.f, 0.f};

#pragma unroll
    for (int pass = 0; pass < 2; ++pass) {
        const ushort_t* a = pass ? agg1b : featb;
        const ushort_t* wt = wT + pass * (128 * 128);
#pragma unroll
        for (int ks = 0; ks < 4; ++ks) {
            int k = ks * 32 + kg;
            bf16x8 a0 = *(const bf16x8*)(a + r0 * 128 + k);
            bf16x8 a1 = *(const bf16x8*)(a + r1 * 128 + k);
#pragma unroll
            for (int nt = 0; nt < 8; ++nt) {
                bf16x8 bb = *(const bf16x8*)(wt + (nt * 16 + lr) * 128 + k);
                acc[0][nt] = __builtin_amdgcn_mfma_f32_16x16x32_bf16(a0, bb, acc[0][nt], 0, 0, 0);
                acc[1][nt] = __builtin_amdgcn_mfma_f32_16x16x32_bf16(a1, bb, acc[1][nt], 0, 0, 0);
            }
        }
    }

    // h1 -> LDS (swizzled), bf16
#pragma unroll
    for (int nt = 0; nt < 8; ++nt) {
        int n = nt * 16 + lr;
        float bias = b1[n];
#pragma unroll
        for (int mt = 0; mt < 2; ++mt) {
#pragma unroll
            for (int r = 0; r < 4; ++r) {
                int lrow = lbase + mt * 16 + drow + r;
                float v = fmaxf(acc[mt][nt][r] + bias, 0.f);
                hlds[lrow][n ^ ((lrow & 7) << 3)] = (ushort_t)f2bf(v);
            }
        }
    }
    __syncthreads();

    // ---- phase 2: p2 = h1@Wn2 ; out = h1@Ws2 + b2 ----
    const ushort_t* wT2 = wT + 32768;  // [WnT2 | WsT2]
    int l0 = lbase + lr;
    int l1 = lbase + 16 + lr;

    f32x4 accP[2][4], accO[2][4];
#pragma unroll
    for (int mt = 0; mt < 2; ++mt)
#pragma unroll
        for (int nt = 0; nt < 4; ++nt) {
            accP[mt][nt] = (f32x4){0.f, 0.f, 0.f, 0.f};
            accO[mt][nt] = (f32x4){0.f, 0.f, 0.f, 0.f};
        }

#pragma unroll
    for (int ks = 0; ks < 4; ++ks) {
        int k = ks * 32 + kg;
        bf16x8 a0 = *(const bf16x8*)(&hlds[l0][k ^ ((l0 & 7) << 3)]);
        bf16x8 a1 = *(const bf16x8*)(&hlds[l1][k ^ ((l1 & 7) << 3)]);
#pragma unroll
        for (int nt = 0; nt < 4; ++nt) {
            bf16x8 bn = *(const bf16x8*)(wT2 + (nt * 16 + lr) * 128 + k);
            bf16x8 bs = *(const bf16x8*)(wT2 + 8192 + (nt * 16 + lr) * 128 + k);
            accP[0][nt] = __builtin_amdgcn_mfma_f32_16x16x32_bf16(a0, bn, accP[0][nt], 0, 0, 0);
            accP[1][nt] = __builtin_amdgcn_mfma_f32_16x16x32_bf16(a1, bn, accP[1][nt], 0, 0, 0);
            accO[0][nt] = __builtin_amdgcn_mfma_f32_16x16x32_bf16(a0, bs, accO[0][nt], 0, 0, 0);
            accO[1][nt] = __builtin_amdgcn_mfma_f32_16x16x32_bf16(a1, bs, accO[1][nt], 0, 0, 0);
        }
    }

#pragma unroll
    for (int nt = 0; nt < 4; ++nt) {
        int n = nt * 16 + lr;
        float bias = b2[n];
#pragma unroll
        for (int mt = 0; mt < 2; ++mt) {
#pragma unroll
            for (int r = 0; r < 4; ++r) {
                int row = mbase + mt * 16 + drow + r;
                if (row < N_NODES) {
                    p2b[(long)row * 64 + n] = (ushort_t)f2bf(accP[mt][nt][r]);
                    out[(long)row * 64 + n] = accO[mt][nt][r] + bias;
                }
            }
        }
    }
}

extern "C" void kernel_launch(void* const* d_in, const int* in_sizes, int n_in,
                              void* d_out, int out_size, void* d_ws, size_t ws_size,
                              hipStream_t stream) {
    const float* feat = (const float*)d_in[0];
    const int* src    = (const int*)d_in[1];
    const int* dst    = (const int*)d_in[2];
    const float* Ws1  = (const float*)d_in[3];
    const float* Wn1  = (const float*)d_in[4];
    const float* b1   = (const float*)d_in[5];
    const float* Ws2  = (const float*)d_in[6];
    const float* Wn2  = (const float*)d_in[7];
    const float* b2   = (const float*)d_in[8];
    float* out = (float*)d_out;

    int* wsi      = (int*)d_ws;
    ushort_t* wsu = (ushort_t*)d_ws;
    int* rowptr       = wsi + IOFF_ROWPTR;
    ushort_t* eidx    = (ushort_t*)(wsi + IOFF_EIDX);
    int* bcnt         = wsi + IOFF_BCNT;
    ushort_t* wT    = wsu + UOFF_WT;
    ushort_t* featb = wsu + UOFF_FEATB;
    ushort_t* agg1b = wsu + UOFF_AGG1B;
    ushort_t* p2b   = wsu + UOFF_P2B;
    uint_t* bucket  = (uint_t*)(wsu + UOFF_BUCKET);  // dead after fill_bucket

    // fused prep: feat -> bf16 + weight transpose/convert + bcnt zeroing
    prep_kernel<<<(NCVT4 + 49152 + NB + 255) / 256, 256, 0, stream>>>(
        feat, Ws1, Wn1, Ws2, Wn2, featb, wT, bcnt);

    // ---- bucketed CSR build ----
    bucket_kernel<<<NBLK_BUCKET, 256, 0, stream>>>(src, dst, bucket, bcnt);
    fill_bucket<<<NB, 1024, 0, stream>>>(bucket, bcnt, rowptr, eidx);

    // ---- layer 1 aggregation ----
    gather128_kernel<<<(N_NODES + 3) / 4, 256, 0, stream>>>(rowptr, eidx, featb, agg1b);

    // ---- fused layer1+layer2 GEMMs (h1 in LDS) ----
    gemm12_mfma<<<(N_NODES + 127) / 128, 256, 0, stream>>>(featb, agg1b, wT, b1, b2, p2b, out);

    // ---- layer 2 aggregation ----
    gather64_add_kernel<<<(N_NODES + 3) / 4, 256, 0, stream>>>(rowptr, eidx, p2b, out);
}

// Round 13
// 197.482 us; speedup vs baseline: 1.9610x; 1.0061x over previous
//
#include <hip/hip_runtime.h>

#define N_NODES 50000
#define N_EDGES 800000
// IN=128, HID=128, OUT=64

typedef unsigned short ushort_t;
typedef unsigned int uint_t;
typedef __attribute__((ext_vector_type(8))) short bf16x8;
typedef __attribute__((ext_vector_type(4))) float f32x4;

#define NB 196        // buckets: dst>>8 (256 nodes per bucket)
#define BCAP 6144     // per-bucket capacity (avg 4082, +safety)
#define SDEPTH 32     // LDS staging depth per bucket
#define EPB 2048      // edges per bucket_kernel block
#define NBLK_BUCKET ((N_EDGES + EPB - 1) / EPB)
#define NCVT4 (N_NODES * 128 / 4)   // 1,600,000 float4 groups for feat cvt

// ---------------- workspace layout ----------------
// int region (int offsets; bytes = x4):
//   rowptr  [50001]   @ 100000   (bytes 400000..600004)
//   eidx    [800000]u16 @ int 150016 (bytes 600064..2200064)
//   bcnt    [196]     @ 950528   (bytes 3802112..3802896)
// bf16 region (ushort offsets; bytes = x2):
//   wT    [49152]     @ 1920000  (bytes 3840000..3938304)
//   featb [50000*128] @ 2000000  (bytes 4000000..16800000)
//   agg1b [50000*128] @ 8400000  (bytes 16800000..29600000)
//   bucket u32[196*6144] @ ushort 14800000 (4.8MB; dead after fill_bucket)
//   p2b   [50000*64]  @ 21200000 (bytes 42400000..48800000)
#define IOFF_ROWPTR  100000
#define IOFF_EIDX    150016
#define IOFF_BCNT    950528
#define UOFF_WT      1920000
#define UOFF_FEATB   2000000
#define UOFF_AGG1B   8400000
#define UOFF_BUCKET  14800000
#define UOFF_P2B     21200000

__device__ __forceinline__ float bf2f(uint_t u) {
    return __uint_as_float(u << 16);
}
__device__ __forceinline__ uint_t f2bf(float f) {
    uint_t x = __float_as_uint(f);
    return (x + 0x7FFFu + ((x >> 16) & 1u)) >> 16;  // RNE
}

// fused prep: feat f32->bf16 + weight transpose/convert + bcnt zeroing
__global__ __launch_bounds__(256) void prep_kernel(const float* __restrict__ feat,
                                                   const float* __restrict__ Ws1,
                                                   const float* __restrict__ Wn1,
                                                   const float* __restrict__ Ws2,
                                                   const float* __restrict__ Wn2,
                                                   ushort_t* __restrict__ featb,
                                                   ushort_t* __restrict__ wT,
                                                   int* __restrict__ bcnt) {
    int i = blockIdx.x * 256 + threadIdx.x;
    if (i < NCVT4) {
        float4 v = ((const float4*)feat)[i];
        uint2 o;
        o.x = f2bf(v.x) | (f2bf(v.y) << 16);
        o.y = f2bf(v.z) | (f2bf(v.w) << 16);
        ((uint2*)featb)[i] = o;
        return;
    }
    int j = i - NCVT4;
    if (j < 49152) {
        float v;
        if (j < 16384) {
            int n = j >> 7, k = j & 127;
            v = Ws1[k * 128 + n];
        } else if (j < 32768) {
            int jj = j - 16384, n = jj >> 7, k = jj & 127;
            v = Wn1[k * 128 + n];
        } else if (j < 40960) {
            int jj = j - 32768, n = jj >> 7, k = jj & 127;
            v = Wn2[k * 64 + n];
        } else {
            int jj = j - 40960, n = jj >> 7, k = jj & 127;
            v = Ws2[k * 64 + n];
        }
        wT[j] = (ushort_t)f2bf(v);
        return;
    }
    int z = j - 49152;
    if (z < NB) bcnt[z] = 0;
}

// ---- bucketed CSR build ----
__global__ __launch_bounds__(256) void bucket_kernel(const int* __restrict__ src,
                                                     const int* __restrict__ dst,
                                                     uint_t* __restrict__ bucket,
                                                     int* __restrict__ bcnt) {
    __shared__ uint_t stage[NB][SDEPTH];
    __shared__ int lcnt[NB];
    __shared__ int gbase[NB];
    int tid = threadIdx.x;
    for (int i = tid; i < NB; i += 256) lcnt[i] = 0;
    __syncthreads();
    int e0 = blockIdx.x * EPB;
#pragma unroll
    for (int it = 0; it < EPB / 256; ++it) {
        int e = e0 + it * 256 + tid;
        if (e < N_EDGES) {
            int d = dst[e], s = src[e];
            uint_t v = ((uint_t)d << 16) | (uint_t)s;
            int b = d >> 8;
            int slot = atomicAdd(&lcnt[b], 1);
            if (slot < SDEPTH) {
                stage[b][slot] = v;
            } else {  // rare overflow: direct reservation
                int p = atomicAdd(&bcnt[b], 1);
                bucket[(long)b * BCAP + p] = v;
            }
        }
    }
    __syncthreads();
    if (tid < NB) {
        int n = min(lcnt[tid], SDEPTH);
        gbase[tid] = (n > 0) ? atomicAdd(&bcnt[tid], n) : 0;
    }
    __syncthreads();
    for (int s = tid; s < NB * SDEPTH; s += 256) {
        int b = s >> 5, i = s & (SDEPTH - 1);
        if (i < min(lcnt[b], SDEPTH))
            bucket[(long)b * BCAP + gbase[b] + i] = stage[b][i];
    }
}

// per-bucket local CSR; block self-computes its bucket base from bcnt scan
__global__ __launch_bounds__(1024) void fill_bucket(const uint_t* __restrict__ bucket,
                                                    const int* __restrict__ bcnt,
                                                    int* __restrict__ rowptr,
                                                    ushort_t* __restrict__ eidx) {
    __shared__ int pref[256];
    __shared__ int hist[256];
    __shared__ int excl[256];
    __shared__ int fp[256];
    int b = blockIdx.x, tid = threadIdx.x;
    if (tid < 256) {
        pref[tid] = (tid < NB) ? bcnt[tid] : 0;
        hist[tid] = 0;
        fp[tid] = 0;
    }
    __syncthreads();
    for (int off = 1; off < 256; off <<= 1) {
        int t = 0;
        if (tid < 256 && tid >= off) t = pref[tid - off];
        __syncthreads();
        if (tid < 256) pref[tid] += t;
        __syncthreads();
    }
    int n = bcnt[b];
    int base = pref[b] - n;  // exclusive base for this bucket
    if (b == NB - 1 && tid == 0) rowptr[N_NODES] = pref[NB - 1];
    int nodebase = b << 8;
    const uint_t* bk = bucket + (long)b * BCAP;
    for (int i = tid; i < n; i += 1024) {
        int d = (int)(bk[i] >> 16) - nodebase;
        atomicAdd(&hist[d], 1);
    }
    __syncthreads();
    int v = 0;
    if (tid < 256) { v = hist[tid]; excl[tid] = v; }
    __syncthreads();
    for (int off = 1; off < 256; off <<= 1) {
        int t = 0;
        if (tid < 256 && tid >= off) t = excl[tid - off];
        __syncthreads();
        if (tid < 256) excl[tid] += t;
        __syncthreads();
    }
    if (tid < 256) {
        excl[tid] -= v;
        int node = nodebase + tid;
        if (node < N_NODES) rowptr[node] = base + excl[tid];
    }
    __syncthreads();
    for (int i = tid; i < n; i += 1024) {
        uint_t vv = bk[i];
        int d = (int)(vv >> 16) - nodebase;
        int off = atomicAdd(&fp[d], 1);
        eidx[base + excl[d] + off] = (ushort_t)(vv & 0xFFFFu);
    }
}

// one wave per node; 16 lanes cover one 256B row (16B/lane), 4 edges per wave-load.
__global__ __launch_bounds__(256) void gather128_kernel(const int* __restrict__ rowptr,
                                                        const ushort_t* __restrict__ eidx,
                                                        const ushort_t* __restrict__ xb,
                                                        ushort_t* __restrict__ aggb) {
    int node = blockIdx.x * 4 + (threadIdx.x >> 6);
    int lane = threadIdx.x & 63;
    if (node >= N_NODES) return;
    int q = lane >> 4;    // edge slot 0..3
    int sl = lane & 15;   // col group: cols sl*8 .. sl*8+7
    int beg = rowptr[node], end = rowptr[node + 1];
    float acc[8];
#pragma unroll
    for (int j = 0; j < 8; ++j) acc[j] = 0.f;

    int e = beg;
    for (; e + 7 < end; e += 8) {
        int sA = eidx[e + q];
        int sB = eidx[e + 4 + q];
        uint4 vA = *(const uint4*)(xb + (long)sA * 128 + sl * 8);
        uint4 vB = *(const uint4*)(xb + (long)sB * 128 + sl * 8);
        acc[0] += bf2f(vA.x & 0xffffu); acc[1] += bf2f(vA.x >> 16);
        acc[2] += bf2f(vA.y & 0xffffu); acc[3] += bf2f(vA.y >> 16);
        acc[4] += bf2f(vA.z & 0xffffu); acc[5] += bf2f(vA.z >> 16);
        acc[6] += bf2f(vA.w & 0xffffu); acc[7] += bf2f(vA.w >> 16);
        acc[0] += bf2f(vB.x & 0xffffu); acc[1] += bf2f(vB.x >> 16);
        acc[2] += bf2f(vB.y & 0xffffu); acc[3] += bf2f(vB.y >> 16);
        acc[4] += bf2f(vB.z & 0xffffu); acc[5] += bf2f(vB.z >> 16);
        acc[6] += bf2f(vB.w & 0xffffu); acc[7] += bf2f(vB.w >> 16);
    }
    for (; e + 3 < end; e += 4) {
        int s = eidx[e + q];
        uint4 v = *(const uint4*)(xb + (long)s * 128 + sl * 8);
        acc[0] += bf2f(v.x & 0xffffu); acc[1] += bf2f(v.x >> 16);
        acc[2] += bf2f(v.y & 0xffffu); acc[3] += bf2f(v.y >> 16);
        acc[4] += bf2f(v.z & 0xffffu); acc[5] += bf2f(v.z >> 16);
        acc[6] += bf2f(v.w & 0xffffu); acc[7] += bf2f(v.w >> 16);
    }
    if (e + q < end) {  // tail: 1..3 edges, slots q < remainder
        int s = eidx[e + q];
        uint4 v = *(const uint4*)(xb + (long)s * 128 + sl * 8);
        acc[0] += bf2f(v.x & 0xffffu); acc[1] += bf2f(v.x >> 16);
        acc[2] += bf2f(v.y & 0xffffu); acc[3] += bf2f(v.y >> 16);
        acc[4] += bf2f(v.z & 0xffffu); acc[5] += bf2f(v.z >> 16);
        acc[6] += bf2f(v.w & 0xffffu); acc[7] += bf2f(v.w >> 16);
    }
#pragma unroll
    for (int j = 0; j < 8; ++j) {
        acc[j] += __shfl_xor(acc[j], 16);
        acc[j] += __shfl_xor(acc[j], 32);
    }
    float inv = (end > beg) ? 1.0f / (float)(end - beg) : 0.f;
    if (lane < 16) {
        uint4 o;
        o.x = f2bf(acc[0] * inv) | (f2bf(acc[1] * inv) << 16);
        o.y = f2bf(acc[2] * inv) | (f2bf(acc[3] * inv) << 16);
        o.z = f2bf(acc[4] * inv) | (f2bf(acc[5] * inv) << 16);
        o.w = f2bf(acc[6] * inv) | (f2bf(acc[7] * inv) << 16);
        *(uint4*)(aggb + (long)node * 128 + sl * 8) = o;
    }
}

// one wave per node; 8 lanes cover one 128B row (16B/lane), 8 edges per wave-load.
__global__ __launch_bounds__(256) void gather64_add_kernel(const int* __restrict__ rowptr,
                                                           const ushort_t* __restrict__ eidx,
                                                           const ushort_t* __restrict__ p2b,
                                                           float* __restrict__ out) {
    int node = blockIdx.x * 4 + (threadIdx.x >> 6);
    int lane = threadIdx.x & 63;
    if (node >= N_NODES) return;
    int q = lane >> 3;    // edge slot 0..7
    int sl = lane & 7;    // col group: cols sl*8 .. sl*8+7
    int beg = rowptr[node], end = rowptr[node + 1];
    float acc[8];
#pragma unroll
    for (int j = 0; j < 8; ++j) acc[j] = 0.f;

    int e = beg;
    for (; e + 15 < end; e += 16) {
        int sA = eidx[e + q];
        int sB = eidx[e + 8 + q];
        uint4 vA = *(const uint4*)(p2b + (long)sA * 64 + sl * 8);
        uint4 vB = *(const uint4*)(p2b + (long)sB * 64 + sl * 8);
        acc[0] += bf2f(vA.x & 0xffffu); acc[1] += bf2f(vA.x >> 16);
        acc[2] += bf2f(vA.y & 0xffffu); acc[3] += bf2f(vA.y >> 16);
        acc[4] += bf2f(vA.z & 0xffffu); acc[5] += bf2f(vA.z >> 16);
        acc[6] += bf2f(vA.w & 0xffffu); acc[7] += bf2f(vA.w >> 16);
        acc[0] += bf2f(vB.x & 0xffffu); acc[1] += bf2f(vB.x >> 16);
        acc[2] += bf2f(vB.y & 0xffffu); acc[3] += bf2f(vB.y >> 16);
        acc[4] += bf2f(vB.z & 0xffffu); acc[5] += bf2f(vB.z >> 16);
        acc[6] += bf2f(vB.w & 0xffffu); acc[7] += bf2f(vB.w >> 16);
    }
    for (; e + 7 < end; e += 8) {
        int s = eidx[e + q];
        uint4 v = *(const uint4*)(p2b + (long)s * 64 + sl * 8);
        acc[0] += bf2f(v.x & 0xffffu); acc[1] += bf2f(v.x >> 16);
        acc[2] += bf2f(v.y & 0xffffu); acc[3] += bf2f(v.y >> 16);
        acc[4] += bf2f(v.z & 0xffffu); acc[5] += bf2f(v.z >> 16);
        acc[6] += bf2f(v.w & 0xffffu); acc[7] += bf2f(v.w >> 16);
    }
    if (e + q < end) {  // tail: 1..7 edges, slots q < remainder
        int s = eidx[e + q];
        uint4 v = *(const uint4*)(p2b + (long)s * 64 + sl * 8);
        acc[0] += bf2f(v.x & 0xffffu); acc[1] += bf2f(v.x >> 16);
        acc[2] += bf2f(v.y & 0xffffu); acc[3] += bf2f(v.y >> 16);
        acc[4] += bf2f(v.z & 0xffffu); acc[5] += bf2f(v.z >> 16);
        acc[6] += bf2f(v.w & 0xffffu); acc[7] += bf2f(v.w >> 16);
    }
#pragma unroll
    for (int j = 0; j < 8; ++j) {
        acc[j] += __shfl_xor(acc[j], 8);
        acc[j] += __shfl_xor(acc[j], 16);
        acc[j] += __shfl_xor(acc[j], 32);
    }
    float inv = (end > beg) ? 1.0f / (float)(end - beg) : 0.f;
    if (lane < 8) {
        float4* po = (float4*)(out + (long)node * 64 + sl * 8);
        float4 o0 = po[0], o1 = po[1];
        o0.x += acc[0] * inv;
        o0.y += acc[1] * inv;
        o0.z += acc[2] * inv;
        o0.w += acc[3] * inv;
        o1.x += acc[4] * inv;
        o1.y += acc[5] * inv;
        o1.z += acc[6] * inv;
        o1.w += acc[7] * inv;
        po[0] = o0;
        po[1] = o1;
    }
}

// ---------------- fused MFMA layers (h1 lives in LDS, never in HBM) ----------------
// A frag (16x16x32 bf16): row = lane&15, k = (lane>>4)*8 + e  -> 16B contiguous
// B frag: col = lane&15, same k                               -> 16B contiguous in W^T
// D frag: col = lane&15, row = (lane>>4)*4 + reg
// h1 LDS tile [128][128] bf16, XOR-swizzled: col' = col ^ ((row&7)<<3)
__global__ __launch_bounds__(256) void gemm12_mfma(const ushort_t* __restrict__ featb,
                                                   const ushort_t* __restrict__ agg1b,
                                                   const ushort_t* __restrict__ wT,
                                                   const float* __restrict__ b1,
                                                   const float* __restrict__ b2,
                                                   ushort_t* __restrict__ p2b,
                                                   float* __restrict__ out) {
    __shared__ ushort_t hlds[128][128];  // 32 KB
    int lane = threadIdx.x & 63;
    int w = threadIdx.x >> 6;
    int mbase = blockIdx.x * 128 + w * 32;
    int lbase = w * 32;          // block-local row base for this wave
    int lr = lane & 15;
    int kg = (lane >> 4) * 8;
    int drow = (lane >> 4) * 4;

    // ---- phase 1: h1 = relu(feat@Ws1 + agg1@Wn1 + b1) ----
    long r0 = mbase + lr;
    long r1 = mbase + 16 + lr;
    if (r0 > N_NODES - 1) r0 = N_NODES - 1;
    if (r1 > N_NODES - 1) r1 = N_NODES - 1;

    f32x4 acc[2][8];
#pragma unroll
    for (int mt = 0; mt < 2; ++mt)
#pragma unroll
        for (int nt = 0; nt < 8; ++nt) acc[mt][nt] = (f32x4){0.f, 0.f, 0.f, 0.f};

#pragma unroll
    for (int pass = 0; pass < 2; ++pass) {
        const ushort_t* a = pass ? agg1b : featb;
        const ushort_t* wt = wT + pass * (128 * 128);
#pragma unroll
        for (int ks = 0; ks < 4; ++ks) {
            int k = ks * 32 + kg;
            bf16x8 a0 = *(const bf16x8*)(a + r0 * 128 + k);
            bf16x8 a1 = *(const bf16x8*)(a + r1 * 128 + k);
#pragma unroll
            for (int nt = 0; nt < 8; ++nt) {
                bf16x8 bb = *(const bf16x8*)(wt + (nt * 16 + lr) * 128 + k);
                acc[0][nt] = __builtin_amdgcn_mfma_f32_16x16x32_bf16(a0, bb, acc[0][nt], 0, 0, 0);
                acc[1][nt] = __builtin_amdgcn_mfma_f32_16x16x32_bf16(a1, bb, acc[1][nt], 0, 0, 0);
            }
        }
    }

    // h1 -> LDS (swizzled), bf16
#pragma unroll
    for (int nt = 0; nt < 8; ++nt) {
        int n = nt * 16 + lr;
        float bias = b1[n];
#pragma unroll
        for (int mt = 0; mt < 2; ++mt) {
#pragma unroll
            for (int r = 0; r < 4; ++r) {
                int lrow = lbase + mt * 16 + drow + r;
                float v = fmaxf(acc[mt][nt][r] + bias, 0.f);
                hlds[lrow][n ^ ((lrow & 7) << 3)] = (ushort_t)f2bf(v);
            }
        }
    }
    __syncthreads();

    // ---- phase 2: p2 = h1@Wn2 ; out = h1@Ws2 + b2 ----
    const ushort_t* wT2 = wT + 32768;  // [WnT2 | WsT2]
    int l0 = lbase + lr;
    int l1 = lbase + 16 + lr;

    f32x4 accP[2][4], accO[2][4];
#pragma unroll
    for (int mt = 0; mt < 2; ++mt)
#pragma unroll
        for (int nt = 0; nt < 4; ++nt) {
            accP[mt][nt] = (f32x4){0.f, 0.f, 0.f, 0.f};
            accO[mt][nt] = (f32x4){0.f, 0.f, 0.f, 0.f};
        }

#pragma unroll
    for (int ks = 0; ks < 4; ++ks) {
        int k = ks * 32 + kg;
        bf16x8 a0 = *(const bf16x8*)(&hlds[l0][k ^ ((l0 & 7) << 3)]);
        bf16x8 a1 = *(const bf16x8*)(&hlds[l1][k ^ ((l1 & 7) << 3)]);
#pragma unroll
        for (int nt = 0; nt < 4; ++nt) {
            bf16x8 bn = *(const bf16x8*)(wT2 + (nt * 16 + lr) * 128 + k);
            bf16x8 bs = *(const bf16x8*)(wT2 + 8192 + (nt * 16 + lr) * 128 + k);
            accP[0][nt] = __builtin_amdgcn_mfma_f32_16x16x32_bf16(a0, bn, accP[0][nt], 0, 0, 0);
            accP[1][nt] = __builtin_amdgcn_mfma_f32_16x16x32_bf16(a1, bn, accP[1][nt], 0, 0, 0);
            accO[0][nt] = __builtin_amdgcn_mfma_f32_16x16x32_bf16(a0, bs, accO[0][nt], 0, 0, 0);
            accO[1][nt] = __builtin_amdgcn_mfma_f32_16x16x32_bf16(a1, bs, accO[1][nt], 0, 0, 0);
        }
    }

#pragma unroll
    for (int nt = 0; nt < 4; ++nt) {
        int n = nt * 16 + lr;
        float bias = b2[n];
#pragma unroll
        for (int mt = 0; mt < 2; ++mt) {
#pragma unroll
            for (int r = 0; r < 4; ++r) {
                int row = mbase + mt * 16 + drow + r;
                if (row < N_NODES) {
                    p2b[(long)row * 64 + n] = (ushort_t)f2bf(accP[mt][nt][r]);
                    out[(long)row * 64 + n] = accO[mt][nt][r] + bias;
                }
            }
        }
    }
}

extern "C" void kernel_launch(void* const* d_in, const int* in_sizes, int n_in,
                              void* d_out, int out_size, void* d_ws, size_t ws_size,
                              hipStream_t stream) {
    const float* feat = (const float*)d_in[0];
    const int* src    = (const int*)d_in[1];
    const int* dst    = (const int*)d_in[2];
    const float* Ws1  = (const float*)d_in[3];
    const float* Wn1  = (const float*)d_in[4];
    const float* b1   = (const float*)d_in[5];
    const float* Ws2  = (const float*)d_in[6];
    const float* Wn2  = (const float*)d_in[7];
    const float* b2   = (const float*)d_in[8];
    float* out = (float*)d_out;

    int* wsi      = (int*)d_ws;
    ushort_t* wsu = (ushort_t*)d_ws;
    int* rowptr       = wsi + IOFF_ROWPTR;
    ushort_t* eidx    = (ushort_t*)(wsi + IOFF_EIDX);
    int* bcnt         = wsi + IOFF_BCNT;
    ushort_t* wT    = wsu + UOFF_WT;
    ushort_t* featb = wsu + UOFF_FEATB;
    ushort_t* agg1b = wsu + UOFF_AGG1B;
    ushort_t* p2b   = wsu + UOFF_P2B;
    uint_t* bucket  = (uint_t*)(wsu + UOFF_BUCKET);  // dead after fill_bucket

    // fused prep: feat -> bf16 + weight transpose/convert + bcnt zeroing
    prep_kernel<<<(NCVT4 + 49152 + NB + 255) / 256, 256, 0, stream>>>(
        feat, Ws1, Wn1, Ws2, Wn2, featb, wT, bcnt);

    // ---- bucketed CSR build ----
    bucket_kernel<<<NBLK_BUCKET, 256, 0, stream>>>(src, dst, bucket, bcnt);
    fill_bucket<<<NB, 1024, 0, stream>>>(bucket, bcnt, rowptr, eidx);

    // ---- layer 1 aggregation ----
    gather128_kernel<<<(N_NODES + 3) / 4, 256, 0, stream>>>(rowptr, eidx, featb, agg1b);

    // ---- fused layer1+layer2 GEMMs (h1 in LDS) ----
    gemm12_mfma<<<(N_NODES + 127) / 128, 256, 0, stream>>>(featb, agg1b, wT, b1, b2, p2b, out);

    // ---- layer 2 aggregation ----
    gather64_add_kernel<<<(N_NODES + 3) / 4, 256, 0, stream>>>(rowptr, eidx, p2b, out);
}